// Round 5
// baseline (310.090 us; speedup 1.0000x reference)
//
#include <hip/hip_runtime.h>
#include <math.h>

#define NCLS 100
#define D 64
#define GACC_FLOATS (NCLS * D * 2 + NCLS)   // 12900: sums[6400] sq[6400] cnt[100]
#define KB1 768        // x-blocks per column-half
#define BLK 256
#define HPART 6400     // per-block partial floats: 100cls x 32col x {sum,sq}

typedef __attribute__((ext_vector_type(8)))  short bf16x8;
typedef __attribute__((ext_vector_type(16))) float f32x16;

#define ZV16 {0.f,0.f,0.f,0.f,0.f,0.f,0.f,0.f,0.f,0.f,0.f,0.f,0.f,0.f,0.f,0.f}

union B8 { uint32_t u[4]; bf16x8 v; };

// packed f32->bf16 RNE; used for BOTH A and B so pair-order convention cancels
__device__ __forceinline__ uint32_t cvtpk(float lo, float hi) {
    uint32_t r;
    asm("v_cvt_pk_bf16_f32 %0, %1, %2" : "=v"(r) : "v"(lo), "v"(hi));
    return r;
}

__device__ __forceinline__ void global_fadd(float* p, float v) {
    asm volatile("global_atomic_add_f32 %0, %1, off"
                 :: "v"((uint64_t)(uintptr_t)p), "v"(v));
}

__device__ __forceinline__ void lds_fadd(uint32_t byteoff, float v) {
    asm volatile("ds_add_f32 %0, %1" :: "v"(byteoff), "v"(v));
}

// ---------------- Kernel 1: segmented sum/sumsq via one-hot MFMA ----------
// grid (KB1, 2): x = slab-range, y = column half. Wave w: classes [32w,32w+32).
// A: row=lane&31, k=(lane>>5)*8+e. B: col=lane&31, same k.
// C/D: col=lane&31, row=(reg&3)+8*(reg>>2)+4*(lane>>5)   [validated R3/R4]
// 2-deep software pipeline: slab s+1 loads issued before slab s compute.
__global__ __launch_bounds__(BLK) void seg_mfma_kernel(
    const float* __restrict__ pred, const int* __restrict__ idx,
    float* __restrict__ part, float* __restrict__ gacc,
    int nrows, int atomicPath)
{
    const int x     = blockIdx.x;
    const int h     = blockIdx.y;
    const int lane  = threadIdx.x & 63;
    const int w     = threadIdx.x >> 6;
    const int col   = lane & 31;
    const int kg    = lane >> 5;
    const int mycls = w * 32 + col;
    const int gcol  = h * 32 + col;

    f32x16 aS = ZV16, aQ = ZV16;

    const size_t nslab = (size_t)nrows >> 4;
    const size_t s0 = (size_t)x * nslab / KB1;
    const size_t s1 = ((size_t)x + 1) * nslab / KB1;

    const float* predg = pred + gcol;

#define LOADSLAB(S, I0, I1, VV)                                          \
    {                                                                    \
        const size_t kb_ = (S) << 4;                                     \
        const int* ip_ = idx + kb_ + (size_t)kg * 8;                     \
        I0 = *(const int4*)ip_;                                          \
        I1 = *(const int4*)(ip_ + 4);                                    \
        const float* pb_ = predg + ((kb_ + (size_t)kg * 8) << 6);        \
        _Pragma("unroll")                                                \
        for (int e_ = 0; e_ < 8; ++e_) VV[e_] = pb_[(size_t)e_ * 64];    \
    }

    int4 ci0, ci1; float cv[8];
    if (s0 < s1) LOADSLAB(s0, ci0, ci1, cv)

    for (size_t s = s0; s < s1; ++s) {
        int4 ni0, ni1; float nv[8];
        if (s + 1 < s1) LOADSLAB(s + 1, ni0, ni1, nv)

        B8 ab, bv, bq;
        ab.u[0] = cvtpk(ci0.x==mycls?1.f:0.f, ci0.y==mycls?1.f:0.f);
        ab.u[1] = cvtpk(ci0.z==mycls?1.f:0.f, ci0.w==mycls?1.f:0.f);
        ab.u[2] = cvtpk(ci1.x==mycls?1.f:0.f, ci1.y==mycls?1.f:0.f);
        ab.u[3] = cvtpk(ci1.z==mycls?1.f:0.f, ci1.w==mycls?1.f:0.f);
        #pragma unroll
        for (int e = 0; e < 4; ++e) {
            bv.u[e] = cvtpk(cv[2*e],          cv[2*e+1]);
            bq.u[e] = cvtpk(cv[2*e]*cv[2*e],  cv[2*e+1]*cv[2*e+1]);
        }
        aS = __builtin_amdgcn_mfma_f32_32x32x16_bf16(ab.v, bv.v, aS, 0, 0, 0);
        aQ = __builtin_amdgcn_mfma_f32_32x32x16_bf16(ab.v, bq.v, aQ, 0, 0, 0);

        ci0 = ni0; ci1 = ni1;
        #pragma unroll
        for (int e = 0; e < 8; ++e) cv[e] = nv[e];
    }
#undef LOADSLAB

    // tail rows (nrows % 16), last x-block, masked
    if (x == KB1 - 1 && (nrows & 15)) {
        const size_t kb = nslab << 4;
        int c[8]; float v[8];
        #pragma unroll
        for (int e = 0; e < 8; ++e) {
            size_t kk = kb + (size_t)kg * 8 + e;
            bool ok = kk < (size_t)nrows;
            c[e] = ok ? idx[kk] : -1;
            v[e] = ok ? pred[(kk << 6) + gcol] : 0.0f;
        }
        B8 ab, bv, bq;
        #pragma unroll
        for (int e = 0; e < 4; ++e) {
            ab.u[e] = cvtpk(c[2*e]==mycls?1.f:0.f, c[2*e+1]==mycls?1.f:0.f);
            bv.u[e] = cvtpk(v[2*e],        v[2*e+1]);
            bq.u[e] = cvtpk(v[2*e]*v[2*e], v[2*e+1]*v[2*e+1]);
        }
        aS = __builtin_amdgcn_mfma_f32_32x32x16_bf16(ab.v, bv.v, aS, 0, 0, 0);
        aQ = __builtin_amdgcn_mfma_f32_32x32x16_bf16(ab.v, bq.v, aQ, 0, 0, 0);
    }

    // epilogue: coalesced per-block partials (or atomic fallback)
    if (!atomicPath) {
        float* pp = part + ((size_t)h * KB1 + x) * HPART;
        #pragma unroll
        for (int reg = 0; reg < 16; ++reg) {
            int row = (reg & 3) + 8 * (reg >> 2) + 4 * kg;
            int gm  = w * 32 + row;
            if (gm < NCLS) {
                pp[gm * 32 + col]        = aS[reg];
                pp[3200 + gm * 32 + col] = aQ[reg];
            }
        }
    } else {
        #pragma unroll
        for (int reg = 0; reg < 16; ++reg) {
            int row = (reg & 3) + 8 * (reg >> 2) + 4 * kg;
            int gm  = w * 32 + row;
            if (gm < NCLS) {
                global_fadd(&gacc[gm * D + gcol],        aS[reg]);
                global_fadd(&gacc[6400 + gm * D + gcol], aQ[reg]);
            }
        }
    }
}

// ---------------- Kernel 1b: class counts (LDS u32 histogram) -------------
__global__ __launch_bounds__(256) void hist_kernel(
    const int* __restrict__ idx, float* __restrict__ gcnt, int nrows)
{
    __shared__ uint32_t hh[NCLS];
    for (int i = threadIdx.x; i < NCLS; i += 256) hh[i] = 0u;
    __syncthreads();

    const int tid = blockIdx.x * 256 + threadIdx.x;
    const int stride = gridDim.x * 256;
    const int n4 = nrows >> 2;
    for (int i = tid; i < n4; i += stride) {
        int4 c = ((const int4*)idx)[i];
        atomicAdd(&hh[c.x], 1u); atomicAdd(&hh[c.y], 1u);
        atomicAdd(&hh[c.z], 1u); atomicAdd(&hh[c.w], 1u);
    }
    for (int i = (n4 << 2) + tid; i < nrows; i += stride)
        atomicAdd(&hh[idx[i]], 1u);
    __syncthreads();

    for (int i = threadIdx.x; i < NCLS; i += 256)
        if (hh[i]) global_fadd(&gcnt[i], (float)hh[i]);
}

// -------- Kernel 1c: reduce partials, 4-way parallel over b-range ---------
// grid (ceil(2*HPART/256), 4); each (pos, quarter) sums 192 blocks' partials
// and atomically adds into gacc (zeroed by the graph's memset each call).
__global__ __launch_bounds__(256) void reduce_kernel(
    const float* __restrict__ part, float* __restrict__ gacc)
{
    int pos = blockIdx.x * 256 + threadIdx.x;    // 0..12799
    if (pos >= 2 * HPART) return;
    int h  = pos / HPART;
    int lp = pos - h * HPART;

    const int bq  = KB1 / 4;                     // 192
    int b0 = blockIdx.y * bq;

    const float* p = part + ((size_t)h * KB1 + b0) * HPART + lp;
    float s0 = 0.f, s1 = 0.f, s2 = 0.f, s3 = 0.f;
    #pragma unroll 1
    for (int b = 0; b + 4 <= bq; b += 4) {
        s0 += p[(size_t)(b + 0) * HPART];
        s1 += p[(size_t)(b + 1) * HPART];
        s2 += p[(size_t)(b + 2) * HPART];
        s3 += p[(size_t)(b + 3) * HPART];
    }
    float s = (s0 + s1) + (s2 + s3);

    int isq = lp >= 3200;
    int ll  = lp - isq * 3200;
    int c   = ll >> 5;
    int d   = (ll & 31) + h * 32;
    global_fadd(&gacc[isq * 6400 + c * D + d], s);
}

// ---------------- Kernel 2: finalize (unchanged, verified) ----------------
#define MSTR 68

__global__ __launch_bounds__(1024) void finalize_kernel(
    const float* __restrict__ gacc, float* __restrict__ out)
{
    __shared__ float mean_s[NCLS * MSTR];
    __shared__ float colstd[D];
    __shared__ float norms[NCLS];
    __shared__ float redSum[16], redMin[16];
    __shared__ float s_cov;

    const float* gSum = gacc;
    const float* gSq  = gacc + NCLS * D;
    const float* gCnt = gacc + 2 * NCLS * D;

    for (int d = threadIdx.x; d < D; d += 1024) colstd[d] = 0.0f;
    __syncthreads();

    for (int i = threadIdx.x; i < NCLS * D; i += 1024) {
        int c = i >> 6, d = i & 63;
        float cnt = gCnt[c];
        float m   = gSum[i] / cnt;
        float var = (gSq[i] - cnt * m * m) / (cnt - 1.0f);
        float sd  = sqrtf(fmaxf(var, 0.0f));
        mean_s[c * MSTR + d] = m;
        lds_fadd((uint32_t)(uintptr_t)(&colstd[d]), sd);
    }
    asm volatile("s_waitcnt lgkmcnt(0)" ::: "memory");
    __syncthreads();

    if (threadIdx.x < 64) {
        float v = colstd[threadIdx.x];
        v = v * v;
        for (int o = 32; o; o >>= 1) v += __shfl_down(v, o);
        if (threadIdx.x == 0) s_cov = v / (float)NCLS;
    }

    for (int c = threadIdx.x; c < NCLS; c += 1024) {
        const float4* mp = (const float4*)&mean_s[c * MSTR];
        float n = 0.0f;
        #pragma unroll
        for (int d4 = 0; d4 < D / 4; ++d4) {
            float4 a = mp[d4];
            n += a.x * a.x + a.y * a.y + a.z * a.z + a.w * a.w;
        }
        norms[c] = n;
    }
    __syncthreads();

    const int n_pairs = NCLS * (NCLS - 1) / 2;
    float lsum = 0.0f, lmin = INFINITY;
    for (int p = threadIdx.x; p < n_pairs; p += 1024) {
        int i = (int)((1.0f + sqrtf(1.0f + 8.0f * (float)p)) * 0.5f);
        while (i * (i - 1) / 2 > p) --i;
        while ((i + 1) * i / 2 <= p) ++i;
        int j = p - i * (i - 1) / 2;

        const float4* mi = (const float4*)&mean_s[i * MSTR];
        const float4* mj = (const float4*)&mean_s[j * MSTR];
        float dot = 0.0f;
        #pragma unroll
        for (int d4 = 0; d4 < D / 4; ++d4) {
            float4 a = mi[d4], b = mj[d4];
            dot += a.x * b.x + a.y * b.y + a.z * b.z + a.w * b.w;
        }
        float dist = norms[i] + norms[j] - 2.0f * dot;
        lsum += dist;
        lmin = fminf(lmin, dist);
    }

    for (int o = 32; o; o >>= 1) {
        lsum += __shfl_down(lsum, o);
        lmin = fminf(lmin, __shfl_down(lmin, o));
    }
    int ww = threadIdx.x >> 6;
    if ((threadIdx.x & 63) == 0) { redSum[ww] = lsum; redMin[ww] = lmin; }
    __syncthreads();

    if (threadIdx.x == 0) {
        float S = 0.0f, M = INFINITY;
        for (int k = 0; k < 16; ++k) { S += redSum[k]; M = fminf(M, redMin[k]); }
        float md  = S / (float)n_pairs;
        float cov = s_cov;
        float e   = 8.0f - md;
        float loss = 1.0f * cov + 0.1f * e * e;   // C_COEF = 0
        out[0] = loss;
        out[1] = md;
        out[2] = M;
        out[3] = cov;
    }
}

extern "C" void kernel_launch(void* const* d_in, const int* in_sizes, int n_in,
                              void* d_out, int out_size, void* d_ws, size_t ws_size,
                              hipStream_t stream) {
    const float* pred = (const float*)d_in[0];
    const int*   gidx = (const int*)d_in[1];
    float* out = (float*)d_out;
    int nrows = in_sizes[1];   // 2,000,000 rows

    const size_t partFloats = (size_t)2 * KB1 * HPART;   // 9,830,400 = 39.32 MB
    dim3 grid1(KB1, 2);

    if (ws_size >= (partFloats + GACC_FLOATS) * sizeof(float)) {
        float* part = (float*)d_ws;
        float* gacc = part + partFloats;
        hipMemsetAsync(gacc, 0, GACC_FLOATS * sizeof(float), stream);
        seg_mfma_kernel<<<grid1, BLK, 0, stream>>>(pred, gidx, part, gacc, nrows, 0);
        hist_kernel<<<1024, 256, 0, stream>>>(gidx, gacc + 2 * NCLS * D, nrows);
        dim3 gridR((2 * HPART + 255) / 256, 4);
        reduce_kernel<<<gridR, 256, 0, stream>>>(part, gacc);
        finalize_kernel<<<1, 1024, 0, stream>>>(gacc, out);
    } else {
        float* gacc = (float*)d_ws;
        hipMemsetAsync(gacc, 0, GACC_FLOATS * sizeof(float), stream);
        seg_mfma_kernel<<<grid1, BLK, 0, stream>>>(pred, gidx, nullptr, gacc, nrows, 1);
        hist_kernel<<<1024, 256, 0, stream>>>(gidx, gacc + 2 * NCLS * D, nrows);
        finalize_kernel<<<1, 1024, 0, stream>>>(gacc, out);
    }
}

// Round 6
// 199.437 us; speedup vs baseline: 1.5548x; 1.5548x over previous
//
#include <hip/hip_runtime.h>
#include <math.h>

#define NCLS 100
#define D 64
#define GACC_FLOATS (NCLS * D * 2 + NCLS)   // 12900: sums[6400] sq[6400] cnt[100]
#define G1 1024        // seg blocks
#define BLK 256
#define PBLK 12800     // per-block partial floats: 100cls x 64col x {sum,sq}

typedef __attribute__((ext_vector_type(8)))  short bf16x8;
typedef __attribute__((ext_vector_type(16))) float f32x16;

#define ZV16 {0.f,0.f,0.f,0.f,0.f,0.f,0.f,0.f,0.f,0.f,0.f,0.f,0.f,0.f,0.f,0.f}

union B8 { uint32_t u[4]; bf16x8 v; };

// packed f32->bf16 RNE; used for BOTH A and B so pair-order convention cancels
__device__ __forceinline__ uint32_t cvtpk(float lo, float hi) {
    uint32_t r;
    asm("v_cvt_pk_bf16_f32 %0, %1, %2" : "=v"(r) : "v"(lo), "v"(hi));
    return r;
}

__device__ __forceinline__ void global_fadd(float* p, float v) {
    asm volatile("global_atomic_add_f32 %0, %1, off"
                 :: "v"((uint64_t)(uintptr_t)p), "v"(v));
}

__device__ __forceinline__ void lds_fadd(uint32_t byteoff, float v) {
    asm volatile("ds_add_f32 %0, %1" :: "v"(byteoff), "v"(v));
}

struct IdxRegs { int4 a, b, c, d; };   // kk=0:{a,b}, kk=1:{c,d} for this lane's kg

__device__ __forceinline__ IdxRegs load_idx(const int* __restrict__ idx, size_t tile, int kg) {
    const int* p = idx + tile * 32 + (size_t)kg * 8;
    IdxRegs r;
    r.a = *(const int4*)p;        r.b = *(const int4*)(p + 4);
    r.c = *(const int4*)(p + 16); r.d = *(const int4*)(p + 20);
    return r;
}

// async stage of one 32x64 f32 tile (8 KB) into LDS, linear layout.
// LDS dest must be wave-uniform base (+ lane*16 by HW); global src per-lane.
__device__ __forceinline__ void stage_tile(const float* __restrict__ pred, size_t tile,
                                           float* pb, int w, int lane) {
    const float* src = pred + tile * 2048;   // 32*64 floats
    #pragma unroll
    for (int r = 0; r < 2; ++r) {
        const float* gs = src + (size_t)(r * 4 + w) * 256 + (size_t)lane * 4;
        float* ls = pb + (r * 4 + w) * 256;
        __builtin_amdgcn_global_load_lds(
            (const __attribute__((address_space(1))) uint32_t*)gs,
            (__attribute__((address_space(3))) uint32_t*)ls, 16, 0, 0);
    }
}

// ---------------- Kernel 1: segmented sum/sumsq via one-hot MFMA ----------
// One block = 4 waves, full D=64. Wave w: classes [32w,32w+32), 4 accs
// (sum,sq) x (coltile 0,1). A: row=lane&31(class), k=(lane>>5)*8+e.
// B: col=lane&31, same k. C/D: col=lane&31, row=(reg&3)+8*(reg>>2)+4*(lane>>5).
// [fragment conventions validated R3-R5, absmax 0]
__global__ __launch_bounds__(BLK, 3) void seg_mfma_kernel(
    const float* __restrict__ pred, const int* __restrict__ idx,
    float* __restrict__ part, float* __restrict__ gacc,
    int nrows, int atomicPath)
{
    __shared__ float pbuf[2][2048];

    const int bid   = blockIdx.x;
    const int tid   = threadIdx.x;
    const int lane  = tid & 63;
    const int w     = tid >> 6;
    const int col   = lane & 31;
    const int kg    = lane >> 5;
    const int mycls = w * 32 + col;

    f32x16 aS0 = ZV16, aS1 = ZV16, aQ0 = ZV16, aQ1 = ZV16;

    const size_t nt = (size_t)(nrows >> 5);          // full 32-row tiles
    const size_t t0 = (size_t)bid * nt / G1;
    const size_t t1 = ((size_t)bid + 1) * nt / G1;

    if (t0 < t1) {
        stage_tile(pred, t0, pbuf[0], w, lane);
        IdxRegs ir = load_idx(idx, t0, kg);
        __syncthreads();                              // drains stage (vmcnt 0)

        int cur = 0;
        for (size_t t = t0; t < t1; ++t) {
            IdxRegs irn = ir;
            if (t + 1 < t1) {
                stage_tile(pred, t + 1, pbuf[cur ^ 1], w, lane);  // async
                irn = load_idx(idx, t + 1, kg);
            }

            const float* pb = pbuf[cur];
            #pragma unroll
            for (int kk = 0; kk < 2; ++kk) {
                const int4 i0 = kk ? ir.c : ir.a;
                const int4 i1 = kk ? ir.d : ir.b;
                B8 ab;
                ab.u[0] = cvtpk(i0.x==mycls?1.f:0.f, i0.y==mycls?1.f:0.f);
                ab.u[1] = cvtpk(i0.z==mycls?1.f:0.f, i0.w==mycls?1.f:0.f);
                ab.u[2] = cvtpk(i1.x==mycls?1.f:0.f, i1.y==mycls?1.f:0.f);
                ab.u[3] = cvtpk(i1.z==mycls?1.f:0.f, i1.w==mycls?1.f:0.f);

                const float* base = pb + (kk * 16 + kg * 8) * 64 + col;
                #pragma unroll
                for (int n = 0; n < 2; ++n) {
                    float v[8];
                    #pragma unroll
                    for (int e = 0; e < 8; ++e) v[e] = base[e * 64 + n * 32]; // bank=col%32: conflict-free
                    B8 bv, bq;
                    #pragma unroll
                    for (int e = 0; e < 4; ++e) {
                        bv.u[e] = cvtpk(v[2*e],         v[2*e+1]);
                        bq.u[e] = cvtpk(v[2*e]*v[2*e],  v[2*e+1]*v[2*e+1]);
                    }
                    if (n == 0) {
                        aS0 = __builtin_amdgcn_mfma_f32_32x32x16_bf16(ab.v, bv.v, aS0, 0, 0, 0);
                        aQ0 = __builtin_amdgcn_mfma_f32_32x32x16_bf16(ab.v, bq.v, aQ0, 0, 0, 0);
                    } else {
                        aS1 = __builtin_amdgcn_mfma_f32_32x32x16_bf16(ab.v, bv.v, aS1, 0, 0, 0);
                        aQ1 = __builtin_amdgcn_mfma_f32_32x32x16_bf16(ab.v, bq.v, aQ1, 0, 0, 0);
                    }
                }
            }
            __syncthreads();     // all waves done with cur; next stage landed
            ir = irn; cur ^= 1;
        }
    }

    // tail rows (nrows % 32), block 0 only, masked direct loads
    if (bid == 0 && (nrows & 31)) {
        for (size_t base = nt * 32; base < (size_t)nrows; base += 16) {
            int c[8]; float v0[8], v1[8];
            #pragma unroll
            for (int e = 0; e < 8; ++e) {
                size_t kk = base + (size_t)kg * 8 + e;
                bool ok = kk < (size_t)nrows;
                c[e]  = ok ? idx[kk] : -1;
                v0[e] = ok ? pred[kk * 64 + col] : 0.0f;
                v1[e] = ok ? pred[kk * 64 + 32 + col] : 0.0f;
            }
            B8 ab, b0, q0, b1, q1;
            #pragma unroll
            for (int e = 0; e < 4; ++e) {
                ab.u[e] = cvtpk(c[2*e]==mycls?1.f:0.f, c[2*e+1]==mycls?1.f:0.f);
                b0.u[e] = cvtpk(v0[2*e],          v0[2*e+1]);
                q0.u[e] = cvtpk(v0[2*e]*v0[2*e],  v0[2*e+1]*v0[2*e+1]);
                b1.u[e] = cvtpk(v1[2*e],          v1[2*e+1]);
                q1.u[e] = cvtpk(v1[2*e]*v1[2*e],  v1[2*e+1]*v1[2*e+1]);
            }
            aS0 = __builtin_amdgcn_mfma_f32_32x32x16_bf16(ab.v, b0.v, aS0, 0, 0, 0);
            aQ0 = __builtin_amdgcn_mfma_f32_32x32x16_bf16(ab.v, q0.v, aQ0, 0, 0, 0);
            aS1 = __builtin_amdgcn_mfma_f32_32x32x16_bf16(ab.v, b1.v, aS1, 0, 0, 0);
            aQ1 = __builtin_amdgcn_mfma_f32_32x32x16_bf16(ab.v, q1.v, aQ1, 0, 0, 0);
        }
    }

    // epilogue: coalesced per-block partials (or atomic fallback)
    if (!atomicPath) {
        float* pp = part + (size_t)bid * PBLK;
        #pragma unroll
        for (int reg = 0; reg < 16; ++reg) {
            int row = (reg & 3) + 8 * (reg >> 2) + 4 * kg;
            int gm  = w * 32 + row;
            if (gm < NCLS) {
                pp[gm * 64 + col]              = aS0[reg];
                pp[gm * 64 + 32 + col]         = aS1[reg];
                pp[6400 + gm * 64 + col]       = aQ0[reg];
                pp[6400 + gm * 64 + 32 + col]  = aQ1[reg];
            }
        }
    } else {
        #pragma unroll
        for (int reg = 0; reg < 16; ++reg) {
            int row = (reg & 3) + 8 * (reg >> 2) + 4 * kg;
            int gm  = w * 32 + row;
            if (gm < NCLS) {
                global_fadd(&gacc[gm * 64 + col],             aS0[reg]);
                global_fadd(&gacc[gm * 64 + 32 + col],        aS1[reg]);
                global_fadd(&gacc[6400 + gm * 64 + col],      aQ0[reg]);
                global_fadd(&gacc[6400 + gm * 64 + 32 + col], aQ1[reg]);
            }
        }
    }
}

// ---------------- Kernel 1b: class counts (LDS u32 histogram) -------------
__global__ __launch_bounds__(256) void hist_kernel(
    const int* __restrict__ idx, float* __restrict__ gcnt, int nrows)
{
    __shared__ uint32_t hh[NCLS];
    for (int i = threadIdx.x; i < NCLS; i += 256) hh[i] = 0u;
    __syncthreads();

    const int tid = blockIdx.x * 256 + threadIdx.x;
    const int stride = gridDim.x * 256;
    const int n4 = nrows >> 2;
    for (int i = tid; i < n4; i += stride) {
        int4 c = ((const int4*)idx)[i];
        atomicAdd(&hh[c.x], 1u); atomicAdd(&hh[c.y], 1u);
        atomicAdd(&hh[c.z], 1u); atomicAdd(&hh[c.w], 1u);
    }
    for (int i = (n4 << 2) + tid; i < nrows; i += stride)
        atomicAdd(&hh[idx[i]], 1u);
    __syncthreads();

    for (int i = threadIdx.x; i < NCLS; i += 256)
        if (hh[i]) global_fadd(&gcnt[i], (float)hh[i]);
}

// -------- Kernel 1c: reduce partials, 8-way parallel over blocks ----------
// part layout [G1][PBLK]; pos layout == gacc layout (sum: c*64+d; sq: +6400).
__global__ __launch_bounds__(256) void reduce_kernel(
    const float* __restrict__ part, float* __restrict__ gacc)
{
    int pos = blockIdx.x * 256 + threadIdx.x;    // 0..12799
    if (pos >= PBLK) return;
    const int bq = G1 / 8;                       // 128
    int b0 = blockIdx.y * bq;

    const float* p = part + (size_t)b0 * PBLK + pos;
    float s0 = 0.f, s1 = 0.f, s2 = 0.f, s3 = 0.f;
    #pragma unroll 1
    for (int b = 0; b + 4 <= bq; b += 4) {
        s0 += p[(size_t)(b + 0) * PBLK];
        s1 += p[(size_t)(b + 1) * PBLK];
        s2 += p[(size_t)(b + 2) * PBLK];
        s3 += p[(size_t)(b + 3) * PBLK];
    }
    global_fadd(&gacc[pos], (s0 + s1) + (s2 + s3));
}

// ---------------- Kernel 2: finalize (unchanged, verified) ----------------
#define MSTR 68

__global__ __launch_bounds__(1024) void finalize_kernel(
    const float* __restrict__ gacc, float* __restrict__ out)
{
    __shared__ float mean_s[NCLS * MSTR];
    __shared__ float colstd[D];
    __shared__ float norms[NCLS];
    __shared__ float redSum[16], redMin[16];
    __shared__ float s_cov;

    const float* gSum = gacc;
    const float* gSq  = gacc + NCLS * D;
    const float* gCnt = gacc + 2 * NCLS * D;

    for (int d = threadIdx.x; d < D; d += 1024) colstd[d] = 0.0f;
    __syncthreads();

    for (int i = threadIdx.x; i < NCLS * D; i += 1024) {
        int c = i >> 6, d = i & 63;
        float cnt = gCnt[c];
        float m   = gSum[i] / cnt;
        float var = (gSq[i] - cnt * m * m) / (cnt - 1.0f);
        float sd  = sqrtf(fmaxf(var, 0.0f));
        mean_s[c * MSTR + d] = m;
        lds_fadd((uint32_t)(uintptr_t)(&colstd[d]), sd);
    }
    asm volatile("s_waitcnt lgkmcnt(0)" ::: "memory");
    __syncthreads();

    if (threadIdx.x < 64) {
        float v = colstd[threadIdx.x];
        v = v * v;
        for (int o = 32; o; o >>= 1) v += __shfl_down(v, o);
        if (threadIdx.x == 0) s_cov = v / (float)NCLS;
    }

    for (int c = threadIdx.x; c < NCLS; c += 1024) {
        const float4* mp = (const float4*)&mean_s[c * MSTR];
        float n = 0.0f;
        #pragma unroll
        for (int d4 = 0; d4 < D / 4; ++d4) {
            float4 a = mp[d4];
            n += a.x * a.x + a.y * a.y + a.z * a.z + a.w * a.w;
        }
        norms[c] = n;
    }
    __syncthreads();

    const int n_pairs = NCLS * (NCLS - 1) / 2;
    float lsum = 0.0f, lmin = INFINITY;
    for (int p = threadIdx.x; p < n_pairs; p += 1024) {
        int i = (int)((1.0f + sqrtf(1.0f + 8.0f * (float)p)) * 0.5f);
        while (i * (i - 1) / 2 > p) --i;
        while ((i + 1) * i / 2 <= p) ++i;
        int j = p - i * (i - 1) / 2;

        const float4* mi = (const float4*)&mean_s[i * MSTR];
        const float4* mj = (const float4*)&mean_s[j * MSTR];
        float dot = 0.0f;
        #pragma unroll
        for (int d4 = 0; d4 < D / 4; ++d4) {
            float4 a = mi[d4], b = mj[d4];
            dot += a.x * b.x + a.y * b.y + a.z * b.z + a.w * b.w;
        }
        float dist = norms[i] + norms[j] - 2.0f * dot;
        lsum += dist;
        lmin = fminf(lmin, dist);
    }

    for (int o = 32; o; o >>= 1) {
        lsum += __shfl_down(lsum, o);
        lmin = fminf(lmin, __shfl_down(lmin, o));
    }
    int ww = threadIdx.x >> 6;
    if ((threadIdx.x & 63) == 0) { redSum[ww] = lsum; redMin[ww] = lmin; }
    __syncthreads();

    if (threadIdx.x == 0) {
        float S = 0.0f, M = INFINITY;
        for (int k = 0; k < 16; ++k) { S += redSum[k]; M = fminf(M, redMin[k]); }
        float md  = S / (float)n_pairs;
        float cov = s_cov;
        float e   = 8.0f - md;
        float loss = 1.0f * cov + 0.1f * e * e;   // C_COEF = 0
        out[0] = loss;
        out[1] = md;
        out[2] = M;
        out[3] = cov;
    }
}

extern "C" void kernel_launch(void* const* d_in, const int* in_sizes, int n_in,
                              void* d_out, int out_size, void* d_ws, size_t ws_size,
                              hipStream_t stream) {
    const float* pred = (const float*)d_in[0];
    const int*   gidx = (const int*)d_in[1];
    float* out = (float*)d_out;
    int nrows = in_sizes[1];   // 2,000,000 rows

    const size_t partFloats = (size_t)G1 * PBLK;   // 13.1M floats = 52.4 MB

    if (ws_size >= (partFloats + GACC_FLOATS) * sizeof(float)) {
        float* part = (float*)d_ws;
        float* gacc = part + partFloats;
        hipMemsetAsync(gacc, 0, GACC_FLOATS * sizeof(float), stream);
        seg_mfma_kernel<<<G1, BLK, 0, stream>>>(pred, gidx, part, gacc, nrows, 0);
        hist_kernel<<<1024, 256, 0, stream>>>(gidx, gacc + 2 * NCLS * D, nrows);
        dim3 gridR((PBLK + 255) / 256, 8);
        reduce_kernel<<<gridR, 256, 0, stream>>>(part, gacc);
        finalize_kernel<<<1, 1024, 0, stream>>>(gacc, out);
    } else {
        float* gacc = (float*)d_ws;
        hipMemsetAsync(gacc, 0, GACC_FLOATS * sizeof(float), stream);
        seg_mfma_kernel<<<G1, BLK, 0, stream>>>(pred, gidx, nullptr, gacc, nrows, 1);
        hist_kernel<<<1024, 256, 0, stream>>>(gidx, gacc + 2 * NCLS * D, nrows);
        finalize_kernel<<<1, 1024, 0, stream>>>(gacc, out);
    }
}

// Round 7
// 188.981 us; speedup vs baseline: 1.6409x; 1.0553x over previous
//
#include <hip/hip_runtime.h>
#include <math.h>

#define NCLS 100
#define D 64
#define GACC_FLOATS (NCLS * D * 2 + NCLS)   // 12900: sums[6400] sq[6400] cnt[100]
#define G1 512         // seg blocks (2 per CU)
#define BLK 256
#define PBLK 12800     // per-block partial floats: 100cls x 64col x {sum,sq}
#define SUPF 8192      // super-tile floats: 128 rows x 64 cols (32 KB)

typedef __attribute__((ext_vector_type(8)))  short bf16x8;
typedef __attribute__((ext_vector_type(16))) float f32x16;

#define ZV16 {0.f,0.f,0.f,0.f,0.f,0.f,0.f,0.f,0.f,0.f,0.f,0.f,0.f,0.f,0.f,0.f}

union B8 { uint32_t u[4]; bf16x8 v; };

// packed f32->bf16 RNE; used for BOTH A and B so pair-order convention cancels
__device__ __forceinline__ uint32_t cvtpk(float lo, float hi) {
    uint32_t r;
    asm("v_cvt_pk_bf16_f32 %0, %1, %2" : "=v"(r) : "v"(lo), "v"(hi));
    return r;
}

__device__ __forceinline__ void global_fadd(float* p, float v) {
    asm volatile("global_atomic_add_f32 %0, %1, off"
                 :: "v"((uint64_t)(uintptr_t)p), "v"(v));
}

__device__ __forceinline__ void lds_fadd(uint32_t byteoff, float v) {
    asm volatile("ds_add_f32 %0, %1" :: "v"(byteoff), "v"(v));
}

struct IdxRegs { int4 a, b, c, d; };   // kk=0:{a,b}, kk=1:{c,d} for this lane's kg

__device__ __forceinline__ IdxRegs load_idx(const int* __restrict__ idx, size_t mtile, int kg) {
    const int* p = idx + mtile * 32 + (size_t)kg * 8;
    IdxRegs r;
    r.a = *(const int4*)p;        r.b = *(const int4*)(p + 4);
    r.c = *(const int4*)(p + 16); r.d = *(const int4*)(p + 20);
    return r;
}

// async stage of one 128x64 f32 super-tile (32 KB) into LDS, linear layout.
// LDS dest = wave-uniform base (+ lane*16 by HW); global src per-lane.
__device__ __forceinline__ void stage_super(const float* __restrict__ pred, size_t st,
                                            float* buf, int w, int lane) {
    const float* src = pred + st * SUPF;
    #pragma unroll
    for (int r = 0; r < 8; ++r) {
        int c = r * 4 + w;                       // 32 chunks of 256 floats
        const float* gs = src + (size_t)c * 256 + (size_t)lane * 4;
        float* ls = buf + c * 256;
        __builtin_amdgcn_global_load_lds(
            (const __attribute__((address_space(1))) uint32_t*)gs,
            (__attribute__((address_space(3))) uint32_t*)ls, 16, 0, 0);
    }
}

// ---------------- Kernel 1: segmented sum/sumsq via one-hot MFMA ----------
// One block = 4 waves, full D=64. Wave w: classes [32w,32w+32), 4 accs
// (sum,sq) x (coltile 0,1). A: row=lane&31(class), k=(lane>>5)*8+e.
// B: col=lane&31, same k. C/D: col=lane&31, row=(reg&3)+8*(reg>>2)+4*(lane>>5).
// [fragment conventions validated R3-R6, absmax 0]
// Super-tile pipeline: ONE barrier per 4 micro-tiles; stage of st+1 in flight
// across ~3000 cyc of compute (T3/T4: avoid per-tile vmcnt-0 drains).
__global__ __launch_bounds__(BLK) void seg_mfma_kernel(
    const float* __restrict__ pred, const int* __restrict__ idx,
    float* __restrict__ part, float* __restrict__ gacc,
    int nrows, int atomicPath)
{
    __shared__ float sbuf[2][SUPF];              // 64 KB -> 2 blocks/CU

    const int bid   = blockIdx.x;
    const int tid   = threadIdx.x;
    const int lane  = tid & 63;
    const int w     = tid >> 6;
    const int col   = lane & 31;
    const int kg    = lane >> 5;
    const int mycls = w * 32 + col;

    f32x16 aS0 = ZV16, aS1 = ZV16, aQ0 = ZV16, aQ1 = ZV16;

    const size_t nst = (size_t)nrows >> 7;       // full 128-row super-tiles
    const size_t st0 = (size_t)bid * nst / G1;
    const size_t st1 = ((size_t)bid + 1) * nst / G1;

    if (st0 < st1) {
        stage_super(pred, st0, sbuf[0], w, lane);
        IdxRegs ir = load_idx(idx, st0 * 4, kg);
        __syncthreads();                         // stage(st0) landed

        int cur = 0;
        for (size_t st = st0; st < st1; ++st) {
            if (st + 1 < st1)
                stage_super(pred, st + 1, sbuf[cur ^ 1], w, lane);   // async

            #pragma unroll
            for (int mt = 0; mt < 4; ++mt) {
                size_t nmt = st * 4 + mt + 1;
                IdxRegs irn = (nmt < st1 * 4) ? load_idx(idx, nmt, kg) : ir;

                const float* pb = sbuf[cur] + mt * 2048;
                #pragma unroll
                for (int kk = 0; kk < 2; ++kk) {
                    const int4 i0 = kk ? ir.c : ir.a;
                    const int4 i1 = kk ? ir.d : ir.b;
                    B8 ab;
                    ab.u[0] = cvtpk(i0.x==mycls?1.f:0.f, i0.y==mycls?1.f:0.f);
                    ab.u[1] = cvtpk(i0.z==mycls?1.f:0.f, i0.w==mycls?1.f:0.f);
                    ab.u[2] = cvtpk(i1.x==mycls?1.f:0.f, i1.y==mycls?1.f:0.f);
                    ab.u[3] = cvtpk(i1.z==mycls?1.f:0.f, i1.w==mycls?1.f:0.f);

                    const float* base = pb + (kk * 16 + kg * 8) * 64 + col;
                    #pragma unroll
                    for (int n = 0; n < 2; ++n) {
                        float v[8];
                        #pragma unroll
                        for (int e = 0; e < 8; ++e) v[e] = base[e * 64 + n * 32]; // 2 lanes/bank: free
                        B8 bv, bq;
                        #pragma unroll
                        for (int e = 0; e < 4; ++e) {
                            bv.u[e] = cvtpk(v[2*e],         v[2*e+1]);
                            bq.u[e] = cvtpk(v[2*e]*v[2*e],  v[2*e+1]*v[2*e+1]);
                        }
                        if (n == 0) {
                            aS0 = __builtin_amdgcn_mfma_f32_32x32x16_bf16(ab.v, bv.v, aS0, 0, 0, 0);
                            aQ0 = __builtin_amdgcn_mfma_f32_32x32x16_bf16(ab.v, bq.v, aQ0, 0, 0, 0);
                        } else {
                            aS1 = __builtin_amdgcn_mfma_f32_32x32x16_bf16(ab.v, bv.v, aS1, 0, 0, 0);
                            aQ1 = __builtin_amdgcn_mfma_f32_32x32x16_bf16(ab.v, bq.v, aQ1, 0, 0, 0);
                        }
                    }
                }
                ir = irn;
            }
            __syncthreads();     // all waves done with cur; stage(st+1) landed
            cur ^= 1;
        }
    }

    // tail rows (nrows % 128), block 0, masked direct loads in 16-row chunks
    if (bid == 0 && (nrows & 127)) {
        for (size_t base = nst * 128; base < (size_t)nrows; base += 16) {
            int c[8]; float v0[8], v1[8];
            #pragma unroll
            for (int e = 0; e < 8; ++e) {
                size_t kk = base + (size_t)kg * 8 + e;
                bool ok = kk < (size_t)nrows;
                c[e]  = ok ? idx[kk] : -1;
                v0[e] = ok ? pred[kk * 64 + col] : 0.0f;
                v1[e] = ok ? pred[kk * 64 + 32 + col] : 0.0f;
            }
            B8 ab, b0, q0, b1, q1;
            #pragma unroll
            for (int e = 0; e < 4; ++e) {
                ab.u[e] = cvtpk(c[2*e]==mycls?1.f:0.f, c[2*e+1]==mycls?1.f:0.f);
                b0.u[e] = cvtpk(v0[2*e],          v0[2*e+1]);
                q0.u[e] = cvtpk(v0[2*e]*v0[2*e],  v0[2*e+1]*v0[2*e+1]);
                b1.u[e] = cvtpk(v1[2*e],          v1[2*e+1]);
                q1.u[e] = cvtpk(v1[2*e]*v1[2*e],  v1[2*e+1]*v1[2*e+1]);
            }
            aS0 = __builtin_amdgcn_mfma_f32_32x32x16_bf16(ab.v, b0.v, aS0, 0, 0, 0);
            aQ0 = __builtin_amdgcn_mfma_f32_32x32x16_bf16(ab.v, q0.v, aQ0, 0, 0, 0);
            aS1 = __builtin_amdgcn_mfma_f32_32x32x16_bf16(ab.v, b1.v, aS1, 0, 0, 0);
            aQ1 = __builtin_amdgcn_mfma_f32_32x32x16_bf16(ab.v, q1.v, aQ1, 0, 0, 0);
        }
    }

    // epilogue: coalesced per-block partials (or atomic fallback)
    if (!atomicPath) {
        float* pp = part + (size_t)bid * PBLK;
        #pragma unroll
        for (int reg = 0; reg < 16; ++reg) {
            int row = (reg & 3) + 8 * (reg >> 2) + 4 * kg;
            int gm  = w * 32 + row;
            if (gm < NCLS) {
                pp[gm * 64 + col]              = aS0[reg];
                pp[gm * 64 + 32 + col]         = aS1[reg];
                pp[6400 + gm * 64 + col]       = aQ0[reg];
                pp[6400 + gm * 64 + 32 + col]  = aQ1[reg];
            }
        }
    } else {
        #pragma unroll
        for (int reg = 0; reg < 16; ++reg) {
            int row = (reg & 3) + 8 * (reg >> 2) + 4 * kg;
            int gm  = w * 32 + row;
            if (gm < NCLS) {
                global_fadd(&gacc[gm * 64 + col],             aS0[reg]);
                global_fadd(&gacc[gm * 64 + 32 + col],        aS1[reg]);
                global_fadd(&gacc[6400 + gm * 64 + col],      aQ0[reg]);
                global_fadd(&gacc[6400 + gm * 64 + 32 + col], aQ1[reg]);
            }
        }
    }
}

// ---------------- Kernel 1b: class counts (LDS u32 histogram) -------------
__global__ __launch_bounds__(256) void hist_kernel(
    const int* __restrict__ idx, float* __restrict__ gcnt, int nrows)
{
    __shared__ uint32_t hh[NCLS];
    for (int i = threadIdx.x; i < NCLS; i += 256) hh[i] = 0u;
    __syncthreads();

    const int tid = blockIdx.x * 256 + threadIdx.x;
    const int stride = gridDim.x * 256;
    const int n4 = nrows >> 2;
    for (int i = tid; i < n4; i += stride) {
        int4 c = ((const int4*)idx)[i];
        atomicAdd(&hh[c.x], 1u); atomicAdd(&hh[c.y], 1u);
        atomicAdd(&hh[c.z], 1u); atomicAdd(&hh[c.w], 1u);
    }
    for (int i = (n4 << 2) + tid; i < nrows; i += stride)
        atomicAdd(&hh[idx[i]], 1u);
    __syncthreads();

    for (int i = threadIdx.x; i < NCLS; i += 256)
        if (hh[i]) global_fadd(&gcnt[i], (float)hh[i]);
}

// -------- Kernel 1c: reduce partials, 8-way parallel over blocks ----------
// part layout [G1][PBLK]; pos layout == gacc layout (sum: c*64+d; sq: +6400).
__global__ __launch_bounds__(256) void reduce_kernel(
    const float* __restrict__ part, float* __restrict__ gacc)
{
    int pos = blockIdx.x * 256 + threadIdx.x;    // 0..12799
    if (pos >= PBLK) return;
    const int bq = G1 / 8;                       // 64
    int b0 = blockIdx.y * bq;

    const float* p = part + (size_t)b0 * PBLK + pos;
    float s0 = 0.f, s1 = 0.f, s2 = 0.f, s3 = 0.f;
    #pragma unroll 1
    for (int b = 0; b + 4 <= bq; b += 4) {
        s0 += p[(size_t)(b + 0) * PBLK];
        s1 += p[(size_t)(b + 1) * PBLK];
        s2 += p[(size_t)(b + 2) * PBLK];
        s3 += p[(size_t)(b + 3) * PBLK];
    }
    global_fadd(&gacc[pos], (s0 + s1) + (s2 + s3));
}

// ---------------- Kernel 2: finalize (unchanged, verified) ----------------
#define MSTR 68

__global__ __launch_bounds__(1024) void finalize_kernel(
    const float* __restrict__ gacc, float* __restrict__ out)
{
    __shared__ float mean_s[NCLS * MSTR];
    __shared__ float colstd[D];
    __shared__ float norms[NCLS];
    __shared__ float redSum[16], redMin[16];
    __shared__ float s_cov;

    const float* gSum = gacc;
    const float* gSq  = gacc + NCLS * D;
    const float* gCnt = gacc + 2 * NCLS * D;

    for (int d = threadIdx.x; d < D; d += 1024) colstd[d] = 0.0f;
    __syncthreads();

    for (int i = threadIdx.x; i < NCLS * D; i += 1024) {
        int c = i >> 6, d = i & 63;
        float cnt = gCnt[c];
        float m   = gSum[i] / cnt;
        float var = (gSq[i] - cnt * m * m) / (cnt - 1.0f);
        float sd  = sqrtf(fmaxf(var, 0.0f));
        mean_s[c * MSTR + d] = m;
        lds_fadd((uint32_t)(uintptr_t)(&colstd[d]), sd);
    }
    asm volatile("s_waitcnt lgkmcnt(0)" ::: "memory");
    __syncthreads();

    if (threadIdx.x < 64) {
        float v = colstd[threadIdx.x];
        v = v * v;
        for (int o = 32; o; o >>= 1) v += __shfl_down(v, o);
        if (threadIdx.x == 0) s_cov = v / (float)NCLS;
    }

    for (int c = threadIdx.x; c < NCLS; c += 1024) {
        const float4* mp = (const float4*)&mean_s[c * MSTR];
        float n = 0.0f;
        #pragma unroll
        for (int d4 = 0; d4 < D / 4; ++d4) {
            float4 a = mp[d4];
            n += a.x * a.x + a.y * a.y + a.z * a.z + a.w * a.w;
        }
        norms[c] = n;
    }
    __syncthreads();

    const int n_pairs = NCLS * (NCLS - 1) / 2;
    float lsum = 0.0f, lmin = INFINITY;
    for (int p = threadIdx.x; p < n_pairs; p += 1024) {
        int i = (int)((1.0f + sqrtf(1.0f + 8.0f * (float)p)) * 0.5f);
        while (i * (i - 1) / 2 > p) --i;
        while ((i + 1) * i / 2 <= p) ++i;
        int j = p - i * (i - 1) / 2;

        const float4* mi = (const float4*)&mean_s[i * MSTR];
        const float4* mj = (const float4*)&mean_s[j * MSTR];
        float dot = 0.0f;
        #pragma unroll
        for (int d4 = 0; d4 < D / 4; ++d4) {
            float4 a = mi[d4], b = mj[d4];
            dot += a.x * b.x + a.y * b.y + a.z * b.z + a.w * b.w;
        }
        float dist = norms[i] + norms[j] - 2.0f * dot;
        lsum += dist;
        lmin = fminf(lmin, dist);
    }

    for (int o = 32; o; o >>= 1) {
        lsum += __shfl_down(lsum, o);
        lmin = fminf(lmin, __shfl_down(lmin, o));
    }
    int ww = threadIdx.x >> 6;
    if ((threadIdx.x & 63) == 0) { redSum[ww] = lsum; redMin[ww] = lmin; }
    __syncthreads();

    if (threadIdx.x == 0) {
        float S = 0.0f, M = INFINITY;
        for (int k = 0; k < 16; ++k) { S += redSum[k]; M = fminf(M, redMin[k]); }
        float md  = S / (float)n_pairs;
        float cov = s_cov;
        float e   = 8.0f - md;
        float loss = 1.0f * cov + 0.1f * e * e;   // C_COEF = 0
        out[0] = loss;
        out[1] = md;
        out[2] = M;
        out[3] = cov;
    }
}

extern "C" void kernel_launch(void* const* d_in, const int* in_sizes, int n_in,
                              void* d_out, int out_size, void* d_ws, size_t ws_size,
                              hipStream_t stream) {
    const float* pred = (const float*)d_in[0];
    const int*   gidx = (const int*)d_in[1];
    float* out = (float*)d_out;
    int nrows = in_sizes[1];   // 2,000,000 rows

    const size_t partFloats = (size_t)G1 * PBLK;   // 6.55M floats = 26.2 MB

    if (ws_size >= (partFloats + GACC_FLOATS) * sizeof(float)) {
        float* part = (float*)d_ws;
        float* gacc = part + partFloats;
        hipMemsetAsync(gacc, 0, GACC_FLOATS * sizeof(float), stream);
        seg_mfma_kernel<<<G1, BLK, 0, stream>>>(pred, gidx, part, gacc, nrows, 0);
        hist_kernel<<<1024, 256, 0, stream>>>(gidx, gacc + 2 * NCLS * D, nrows);
        dim3 gridR((PBLK + 255) / 256, 8);
        reduce_kernel<<<gridR, 256, 0, stream>>>(part, gacc);
        finalize_kernel<<<1, 1024, 0, stream>>>(gacc, out);
    } else {
        float* gacc = (float*)d_ws;
        hipMemsetAsync(gacc, 0, GACC_FLOATS * sizeof(float), stream);
        seg_mfma_kernel<<<G1, BLK, 0, stream>>>(pred, gidx, nullptr, gacc, nrows, 1);
        hist_kernel<<<1024, 256, 0, stream>>>(gidx, gacc + 2 * NCLS * D, nrows);
        finalize_kernel<<<1, 1024, 0, stream>>>(gacc, out);
    }
}

// Round 8
// 174.769 us; speedup vs baseline: 1.7743x; 1.0813x over previous
//
#include <hip/hip_runtime.h>
#include <math.h>

#define NCLS 100
#define D 64
#define GACC_FLOATS (NCLS * D * 2 + NCLS)   // 12900: sums[6400] sq[6400] cnt[100]
#define G1 1024        // seg blocks (4 per CU)
#define BLK 256
#define PBLK 12800     // per-block partial floats: 100cls x 64col x {sum,sq}
#define SUPF 4096      // super-tile floats: 64 rows x 64 cols (16 KB)

typedef __attribute__((ext_vector_type(8)))  short bf16x8;
typedef __attribute__((ext_vector_type(16))) float f32x16;
typedef __attribute__((ext_vector_type(2)))  float f32x2;
typedef __attribute__((ext_vector_type(4)))  int   i32x4;

#define ZV16 {0.f,0.f,0.f,0.f,0.f,0.f,0.f,0.f,0.f,0.f,0.f,0.f,0.f,0.f,0.f,0.f}

union B8 { uint32_t u[4]; bf16x8 v; };

// packed f32->bf16 RNE; used for BOTH A and B so pair-order convention cancels
__device__ __forceinline__ uint32_t cvtpk(float lo, float hi) {
    uint32_t r;
    asm("v_cvt_pk_bf16_f32 %0, %1, %2" : "=v"(r) : "v"(lo), "v"(hi));
    return r;
}

__device__ __forceinline__ void global_fadd(float* p, float v) {
    asm volatile("global_atomic_add_f32 %0, %1, off"
                 :: "v"((uint64_t)(uintptr_t)p), "v"(v));
}

__device__ __forceinline__ void lds_fadd(uint32_t byteoff, float v) {
    asm volatile("ds_add_f32 %0, %1" :: "v"(byteoff), "v"(v));
}

// stage one 64x64 f32 super-tile (16 KB) + its 64 idx ints into LDS.
// 5 gll per wave (idx gll redundant across the 4 waves - same data, benign).
__device__ __forceinline__ void stage_super(const float* __restrict__ pred,
                                            const int* __restrict__ idx, size_t st,
                                            float* sb, int* ib, int w, int lane) {
    const float* src = pred + st * SUPF;
    #pragma unroll
    for (int r = 0; r < 4; ++r) {
        int c = r * 4 + w;                       // 16 chunks of 256 floats
        const float* gs = src + (size_t)c * 256 + (size_t)lane * 4;
        float* ls = sb + c * 256;
        __builtin_amdgcn_global_load_lds(
            (const __attribute__((address_space(1))) uint32_t*)gs,
            (__attribute__((address_space(3))) uint32_t*)ls, 16, 0, 0);
    }
    const int* gi = idx + st * 64 + lane;
    __builtin_amdgcn_global_load_lds(
        (const __attribute__((address_space(1))) uint32_t*)gi,
        (__attribute__((address_space(3))) uint32_t*)ib, 4, 0, 0);
}

// ---------------- Kernel 1: segmented sum/sumsq via one-hot MFMA ----------
// Wave w: classes [32w,32w+32). A: row=lane&31(class), k=(lane>>5)*8+e.
// B: col=lane&31, same k. C/D: col=lane&31, row=(reg&3)+8*(reg>>2)+4*(lane>>5).
// [fragment conventions validated R3-R7, absmax 0]
// Counted-vmcnt pipeline (T3/T4): raw s_barrier, vmcnt(5) NOT 0 in main loop;
// idx staged via gll so the per-wave outstanding count is exact & uniform.
__global__ __launch_bounds__(BLK, 4) void seg_mfma_kernel(
    const float* __restrict__ pred, const int* __restrict__ idx,
    float* __restrict__ part, float* __restrict__ gacc,
    int nrows, int atomicPath)
{
    __shared__ float sbuf[2][SUPF];              // 2 x 16 KB
    __shared__ int   ibuf[2][64];                // 2 x 256 B

    const int bid   = blockIdx.x;
    const int tid   = threadIdx.x;
    const int lane  = tid & 63;
    const int w     = tid >> 6;
    const int col   = lane & 31;
    const int kg    = lane >> 5;
    const int mycls = w * 32 + col;

    f32x16 aS0 = ZV16, aS1 = ZV16, aQ0 = ZV16, aQ1 = ZV16;

    const size_t nst = (size_t)nrows >> 6;       // full 64-row super-tiles
    const size_t st0 = (size_t)bid * nst / G1;
    const size_t st1 = ((size_t)bid + 1) * nst / G1;

    if (st0 < st1) {
        stage_super(pred, idx, st0, sbuf[0], ibuf[0], w, lane);

        int cur = 0;
        for (size_t st = st0; st < st1; ++st) {
            if (st + 1 < st1) {
                stage_super(pred, idx, st + 1, sbuf[cur ^ 1], ibuf[cur ^ 1], w, lane);
                asm volatile("s_waitcnt vmcnt(5)" ::: "memory");   // stage(st) landed; st+1 in flight
            } else {
                asm volatile("s_waitcnt vmcnt(0)" ::: "memory");
            }
            __builtin_amdgcn_sched_barrier(0);
            __builtin_amdgcn_s_barrier();        // RAW: every wave's stage(st) chunk landed

            const uint32_t sb32 = (uint32_t)(uintptr_t)&sbuf[cur][0];
            const uint32_t ib32 = (uint32_t)(uintptr_t)&ibuf[cur][0];

            #pragma unroll
            for (int mt = 0; mt < 2; ++mt) {
                #pragma unroll
                for (int kk = 0; kk < 2; ++kk) {
                    const int rowk = mt * 32 + kk * 16 + kg * 8;
                    const uint32_t ia = ib32 + (uint32_t)(rowk * 4);
                    const uint32_t b0 = sb32 + (uint32_t)(rowk * 256) + (uint32_t)col * 4;

                    i32x4 q0, q1;
                    f32x2 p0, p1, p2, p3, p4, p5, p6, p7;
                    asm volatile("ds_read_b128 %0, %1"            : "=v"(q0) : "v"(ia));
                    asm volatile("ds_read_b128 %0, %1 offset:16"  : "=v"(q1) : "v"(ia));
                    // n=0: k pairs (0,1),(2,3) on b0; (4,5),(6,7) on b0+1024
                    asm volatile("ds_read2_b32 %0, %1 offset0:0 offset1:64"     : "=v"(p0) : "v"(b0));
                    asm volatile("ds_read2_b32 %0, %1 offset0:128 offset1:192"  : "=v"(p1) : "v"(b0));
                    asm volatile("ds_read2_b32 %0, %1 offset0:0 offset1:64"     : "=v"(p2) : "v"(b0 + 1024u));
                    asm volatile("ds_read2_b32 %0, %1 offset0:128 offset1:192"  : "=v"(p3) : "v"(b0 + 1024u));
                    // n=1: +128 B
                    asm volatile("ds_read2_b32 %0, %1 offset0:0 offset1:64"     : "=v"(p4) : "v"(b0 + 128u));
                    asm volatile("ds_read2_b32 %0, %1 offset0:128 offset1:192"  : "=v"(p5) : "v"(b0 + 128u));
                    asm volatile("ds_read2_b32 %0, %1 offset0:0 offset1:64"     : "=v"(p6) : "v"(b0 + 1152u));
                    asm volatile("ds_read2_b32 %0, %1 offset0:128 offset1:192"  : "=v"(p7) : "v"(b0 + 1152u));
                    asm volatile("s_waitcnt lgkmcnt(0)" ::: "memory");
                    __builtin_amdgcn_sched_barrier(0);               // rule #18

                    B8 ab;
                    ab.u[0] = cvtpk(q0.x==mycls?1.f:0.f, q0.y==mycls?1.f:0.f);
                    ab.u[1] = cvtpk(q0.z==mycls?1.f:0.f, q0.w==mycls?1.f:0.f);
                    ab.u[2] = cvtpk(q1.x==mycls?1.f:0.f, q1.y==mycls?1.f:0.f);
                    ab.u[3] = cvtpk(q1.z==mycls?1.f:0.f, q1.w==mycls?1.f:0.f);

                    B8 bv, bq;
                    bv.u[0] = cvtpk(p0.x, p0.y);  bq.u[0] = cvtpk(p0.x*p0.x, p0.y*p0.y);
                    bv.u[1] = cvtpk(p1.x, p1.y);  bq.u[1] = cvtpk(p1.x*p1.x, p1.y*p1.y);
                    bv.u[2] = cvtpk(p2.x, p2.y);  bq.u[2] = cvtpk(p2.x*p2.x, p2.y*p2.y);
                    bv.u[3] = cvtpk(p3.x, p3.y);  bq.u[3] = cvtpk(p3.x*p3.x, p3.y*p3.y);
                    aS0 = __builtin_amdgcn_mfma_f32_32x32x16_bf16(ab.v, bv.v, aS0, 0, 0, 0);
                    aQ0 = __builtin_amdgcn_mfma_f32_32x32x16_bf16(ab.v, bq.v, aQ0, 0, 0, 0);

                    bv.u[0] = cvtpk(p4.x, p4.y);  bq.u[0] = cvtpk(p4.x*p4.x, p4.y*p4.y);
                    bv.u[1] = cvtpk(p5.x, p5.y);  bq.u[1] = cvtpk(p5.x*p5.x, p5.y*p5.y);
                    bv.u[2] = cvtpk(p6.x, p6.y);  bq.u[2] = cvtpk(p6.x*p6.x, p6.y*p6.y);
                    bv.u[3] = cvtpk(p7.x, p7.y);  bq.u[3] = cvtpk(p7.x*p7.x, p7.y*p7.y);
                    aS1 = __builtin_amdgcn_mfma_f32_32x32x16_bf16(ab.v, bv.v, aS1, 0, 0, 0);
                    aQ1 = __builtin_amdgcn_mfma_f32_32x32x16_bf16(ab.v, bq.v, aQ1, 0, 0, 0);
                }
            }
            __builtin_amdgcn_s_barrier();        // WAR: all waves done reading buf[cur]
            cur ^= 1;
        }
    }

    // tail rows (nrows % 64), block 0, masked direct loads (2M % 64 == 0 normally)
    if (bid == 0 && (nrows & 63)) {
        for (size_t base = nst * 64; base < (size_t)nrows; base += 16) {
            int c[8]; float v0[8], v1[8];
            #pragma unroll
            for (int e = 0; e < 8; ++e) {
                size_t kk = base + (size_t)kg * 8 + e;
                bool ok = kk < (size_t)nrows;
                c[e]  = ok ? idx[kk] : -1;
                v0[e] = ok ? pred[kk * 64 + col] : 0.0f;
                v1[e] = ok ? pred[kk * 64 + 32 + col] : 0.0f;
            }
            B8 ab, b0, q0, b1, q1;
            #pragma unroll
            for (int e = 0; e < 4; ++e) {
                ab.u[e] = cvtpk(c[2*e]==mycls?1.f:0.f, c[2*e+1]==mycls?1.f:0.f);
                b0.u[e] = cvtpk(v0[2*e],          v0[2*e+1]);
                q0.u[e] = cvtpk(v0[2*e]*v0[2*e],  v0[2*e+1]*v0[2*e+1]);
                b1.u[e] = cvtpk(v1[2*e],          v1[2*e+1]);
                q1.u[e] = cvtpk(v1[2*e]*v1[2*e],  v1[2*e+1]*v1[2*e+1]);
            }
            aS0 = __builtin_amdgcn_mfma_f32_32x32x16_bf16(ab.v, b0.v, aS0, 0, 0, 0);
            aQ0 = __builtin_amdgcn_mfma_f32_32x32x16_bf16(ab.v, q0.v, aQ0, 0, 0, 0);
            aS1 = __builtin_amdgcn_mfma_f32_32x32x16_bf16(ab.v, b1.v, aS1, 0, 0, 0);
            aQ1 = __builtin_amdgcn_mfma_f32_32x32x16_bf16(ab.v, q1.v, aQ1, 0, 0, 0);
        }
    }

    // epilogue: coalesced per-block partials (or atomic fallback)
    if (!atomicPath) {
        float* pp = part + (size_t)bid * PBLK;
        #pragma unroll
        for (int reg = 0; reg < 16; ++reg) {
            int row = (reg & 3) + 8 * (reg >> 2) + 4 * kg;
            int gm  = w * 32 + row;
            if (gm < NCLS) {
                pp[gm * 64 + col]              = aS0[reg];
                pp[gm * 64 + 32 + col]         = aS1[reg];
                pp[6400 + gm * 64 + col]       = aQ0[reg];
                pp[6400 + gm * 64 + 32 + col]  = aQ1[reg];
            }
        }
    } else {
        #pragma unroll
        for (int reg = 0; reg < 16; ++reg) {
            int row = (reg & 3) + 8 * (reg >> 2) + 4 * kg;
            int gm  = w * 32 + row;
            if (gm < NCLS) {
                global_fadd(&gacc[gm * 64 + col],             aS0[reg]);
                global_fadd(&gacc[gm * 64 + 32 + col],        aS1[reg]);
                global_fadd(&gacc[6400 + gm * 64 + col],      aQ0[reg]);
                global_fadd(&gacc[6400 + gm * 64 + 32 + col], aQ1[reg]);
            }
        }
    }
}

// ---------------- Kernel 1b: class counts (LDS u32 histogram) -------------
__global__ __launch_bounds__(256) void hist_kernel(
    const int* __restrict__ idx, float* __restrict__ gcnt, int nrows)
{
    __shared__ uint32_t hh[NCLS];
    for (int i = threadIdx.x; i < NCLS; i += 256) hh[i] = 0u;
    __syncthreads();

    const int tid = blockIdx.x * 256 + threadIdx.x;
    const int stride = gridDim.x * 256;
    const int n4 = nrows >> 2;
    for (int i = tid; i < n4; i += stride) {
        int4 c = ((const int4*)idx)[i];
        atomicAdd(&hh[c.x], 1u); atomicAdd(&hh[c.y], 1u);
        atomicAdd(&hh[c.z], 1u); atomicAdd(&hh[c.w], 1u);
    }
    for (int i = (n4 << 2) + tid; i < nrows; i += stride)
        atomicAdd(&hh[idx[i]], 1u);
    __syncthreads();

    for (int i = threadIdx.x; i < NCLS; i += 256)
        if (hh[i]) global_fadd(&gcnt[i], (float)hh[i]);
}

// -------- Kernel 1c: reduce partials, 8-way parallel over blocks ----------
// part layout [G1][PBLK]; pos layout == gacc layout (sum: c*64+d; sq: +6400).
__global__ __launch_bounds__(256) void reduce_kernel(
    const float* __restrict__ part, float* __restrict__ gacc)
{
    int pos = blockIdx.x * 256 + threadIdx.x;    // 0..12799
    if (pos >= PBLK) return;
    const int bq = G1 / 8;                       // 128
    int b0 = blockIdx.y * bq;

    const float* p = part + (size_t)b0 * PBLK + pos;
    float s0 = 0.f, s1 = 0.f, s2 = 0.f, s3 = 0.f;
    #pragma unroll 1
    for (int b = 0; b + 4 <= bq; b += 4) {
        s0 += p[(size_t)(b + 0) * PBLK];
        s1 += p[(size_t)(b + 1) * PBLK];
        s2 += p[(size_t)(b + 2) * PBLK];
        s3 += p[(size_t)(b + 3) * PBLK];
    }
    global_fadd(&gacc[pos], (s0 + s1) + (s2 + s3));
}

// ---------------- Kernel 2: finalize (unchanged, verified) ----------------
#define MSTR 68

__global__ __launch_bounds__(1024) void finalize_kernel(
    const float* __restrict__ gacc, float* __restrict__ out)
{
    __shared__ float mean_s[NCLS * MSTR];
    __shared__ float colstd[D];
    __shared__ float norms[NCLS];
    __shared__ float redSum[16], redMin[16];
    __shared__ float s_cov;

    const float* gSum = gacc;
    const float* gSq  = gacc + NCLS * D;
    const float* gCnt = gacc + 2 * NCLS * D;

    for (int d = threadIdx.x; d < D; d += 1024) colstd[d] = 0.0f;
    __syncthreads();

    for (int i = threadIdx.x; i < NCLS * D; i += 1024) {
        int c = i >> 6, d = i & 63;
        float cnt = gCnt[c];
        float m   = gSum[i] / cnt;
        float var = (gSq[i] - cnt * m * m) / (cnt - 1.0f);
        float sd  = sqrtf(fmaxf(var, 0.0f));
        mean_s[c * MSTR + d] = m;
        lds_fadd((uint32_t)(uintptr_t)(&colstd[d]), sd);
    }
    asm volatile("s_waitcnt lgkmcnt(0)" ::: "memory");
    __syncthreads();

    if (threadIdx.x < 64) {
        float v = colstd[threadIdx.x];
        v = v * v;
        for (int o = 32; o; o >>= 1) v += __shfl_down(v, o);
        if (threadIdx.x == 0) s_cov = v / (float)NCLS;
    }

    for (int c = threadIdx.x; c < NCLS; c += 1024) {
        const float4* mp = (const float4*)&mean_s[c * MSTR];
        float n = 0.0f;
        #pragma unroll
        for (int d4 = 0; d4 < D / 4; ++d4) {
            float4 a = mp[d4];
            n += a.x * a.x + a.y * a.y + a.z * a.z + a.w * a.w;
        }
        norms[c] = n;
    }
    __syncthreads();

    const int n_pairs = NCLS * (NCLS - 1) / 2;
    float lsum = 0.0f, lmin = INFINITY;
    for (int p = threadIdx.x; p < n_pairs; p += 1024) {
        int i = (int)((1.0f + sqrtf(1.0f + 8.0f * (float)p)) * 0.5f);
        while (i * (i - 1) / 2 > p) --i;
        while ((i + 1) * i / 2 <= p) ++i;
        int j = p - i * (i - 1) / 2;

        const float4* mi = (const float4*)&mean_s[i * MSTR];
        const float4* mj = (const float4*)&mean_s[j * MSTR];
        float dot = 0.0f;
        #pragma unroll
        for (int d4 = 0; d4 < D / 4; ++d4) {
            float4 a = mi[d4], b = mj[d4];
            dot += a.x * b.x + a.y * b.y + a.z * b.z + a.w * b.w;
        }
        float dist = norms[i] + norms[j] - 2.0f * dot;
        lsum += dist;
        lmin = fminf(lmin, dist);
    }

    for (int o = 32; o; o >>= 1) {
        lsum += __shfl_down(lsum, o);
        lmin = fminf(lmin, __shfl_down(lmin, o));
    }
    int ww = threadIdx.x >> 6;
    if ((threadIdx.x & 63) == 0) { redSum[ww] = lsum; redMin[ww] = lmin; }
    __syncthreads();

    if (threadIdx.x == 0) {
        float S = 0.0f, M = INFINITY;
        for (int k = 0; k < 16; ++k) { S += redSum[k]; M = fminf(M, redMin[k]); }
        float md  = S / (float)n_pairs;
        float cov = s_cov;
        float e   = 8.0f - md;
        float loss = 1.0f * cov + 0.1f * e * e;   // C_COEF = 0
        out[0] = loss;
        out[1] = md;
        out[2] = M;
        out[3] = cov;
    }
}

extern "C" void kernel_launch(void* const* d_in, const int* in_sizes, int n_in,
                              void* d_out, int out_size, void* d_ws, size_t ws_size,
                              hipStream_t stream) {
    const float* pred = (const float*)d_in[0];
    const int*   gidx = (const int*)d_in[1];
    float* out = (float*)d_out;
    int nrows = in_sizes[1];   // 2,000,000 rows

    const size_t partFloats = (size_t)G1 * PBLK;   // 13.1M floats = 52.4 MB

    if (ws_size >= (partFloats + GACC_FLOATS) * sizeof(float)) {
        float* part = (float*)d_ws;
        float* gacc = part + partFloats;
        hipMemsetAsync(gacc, 0, GACC_FLOATS * sizeof(float), stream);
        seg_mfma_kernel<<<G1, BLK, 0, stream>>>(pred, gidx, part, gacc, nrows, 0);
        hist_kernel<<<1024, 256, 0, stream>>>(gidx, gacc + 2 * NCLS * D, nrows);
        dim3 gridR((PBLK + 255) / 256, 8);
        reduce_kernel<<<gridR, 256, 0, stream>>>(part, gacc);
        finalize_kernel<<<1, 1024, 0, stream>>>(gacc, out);
    } else {
        float* gacc = (float*)d_ws;
        hipMemsetAsync(gacc, 0, GACC_FLOATS * sizeof(float), stream);
        seg_mfma_kernel<<<G1, BLK, 0, stream>>>(pred, gidx, nullptr, gacc, nrows, 1);
        hist_kernel<<<1024, 256, 0, stream>>>(gidx, gacc + 2 * NCLS * D, nrows);
        finalize_kernel<<<1, 1024, 0, stream>>>(gacc, out);
    }
}

// Round 9
// 162.397 us; speedup vs baseline: 1.9095x; 1.0762x over previous
//
#include <hip/hip_runtime.h>
#include <math.h>

#define NCLS 100
#define D 64
#define GACC_FLOATS (NCLS * D * 2 + NCLS)   // 12900: sums[6400] sq[6400] cnt[100]
#define G1 1024        // seg blocks
#define BLK 256
#define PBLK 12900     // per-block partial floats: identity layout vs gacc
#define SUPF 4096      // super-tile floats: 64 rows x 64 cols (16 KB)

typedef __attribute__((ext_vector_type(8)))  short bf16x8;
typedef __attribute__((ext_vector_type(16))) float f32x16;
typedef __attribute__((ext_vector_type(2)))  float f32x2;
typedef __attribute__((ext_vector_type(4)))  int   i32x4;

#define ZV16 {0.f,0.f,0.f,0.f,0.f,0.f,0.f,0.f,0.f,0.f,0.f,0.f,0.f,0.f,0.f,0.f}

union B8 { uint32_t u[4]; bf16x8 v; };

// packed f32->bf16 RNE; used for BOTH A and B so pair-order convention cancels
__device__ __forceinline__ uint32_t cvtpk(float lo, float hi) {
    uint32_t r;
    asm("v_cvt_pk_bf16_f32 %0, %1, %2" : "=v"(r) : "v"(lo), "v"(hi));
    return r;
}

__device__ __forceinline__ void global_fadd(float* p, float v) {
    asm volatile("global_atomic_add_f32 %0, %1, off"
                 :: "v"((uint64_t)(uintptr_t)p), "v"(v));
}

__device__ __forceinline__ void lds_fadd(uint32_t byteoff, float v) {
    asm volatile("ds_add_f32 %0, %1" :: "v"(byteoff), "v"(v));
}

// stage one 64x64 f32 super-tile (16 KB) + its 64 idx ints into LDS.
// 5 gll per wave (idx gll redundant across the 4 waves - same data, benign).
__device__ __forceinline__ void stage_super(const float* __restrict__ pred,
                                            const int* __restrict__ idx, size_t st,
                                            float* sb, int* ib, int w, int lane) {
    const float* src = pred + st * SUPF;
    #pragma unroll
    for (int r = 0; r < 4; ++r) {
        int c = r * 4 + w;                       // 16 chunks of 256 floats
        const float* gs = src + (size_t)c * 256 + (size_t)lane * 4;
        float* ls = sb + c * 256;
        __builtin_amdgcn_global_load_lds(
            (const __attribute__((address_space(1))) uint32_t*)gs,
            (__attribute__((address_space(3))) uint32_t*)ls, 16, 0, 0);
    }
    const int* gi = idx + st * 64 + lane;
    __builtin_amdgcn_global_load_lds(
        (const __attribute__((address_space(1))) uint32_t*)gi,
        (__attribute__((address_space(3))) uint32_t*)ib, 4, 0, 0);
}

// ---------------- Kernel 1: segmented sum/sumsq/count via one-hot MFMA ----
// Wave w: classes [32w,32w+32). A: row=lane&31(class), k=(lane>>5)*8+e.
// B: col=lane&31, same k. C/D: col=lane&31, row=(reg&3)+8*(reg>>2)+4*(lane>>5).
// [fragment conventions validated R3-R8, absmax ~0]
// Counted-vmcnt pipeline (T3/T4): raw s_barrier, vmcnt(5) NOT 0 in main loop.
// NO min-waves launch bound: 5 f32x16 accs = 80 AGPR + ~110 VGPR on the
// unified gfx950 file; a (256,4) bound caps at 128 and forces inner-loop
// scratch spills (suspected R8 limiter).
__global__ __launch_bounds__(BLK) void seg_mfma_kernel(
    const float* __restrict__ pred, const int* __restrict__ idx,
    float* __restrict__ part, float* __restrict__ gacc,
    int nrows, int atomicPath)
{
    __shared__ float sbuf[2][SUPF];              // 2 x 16 KB
    __shared__ int   ibuf[2][64];                // 2 x 256 B

    const int bid   = blockIdx.x;
    const int tid   = threadIdx.x;
    const int lane  = tid & 63;
    const int w     = tid >> 6;
    const int col   = lane & 31;
    const int kg    = lane >> 5;
    const int mycls = w * 32 + col;

    f32x16 aS0 = ZV16, aS1 = ZV16, aQ0 = ZV16, aQ1 = ZV16, aC = ZV16;

    B8 ob; ob.u[0] = 0x3F803F80u; ob.u[1] = 0x3F803F80u;
           ob.u[2] = 0x3F803F80u; ob.u[3] = 0x3F803F80u;
    const bf16x8 ones = ob.v;

    const size_t nst = (size_t)nrows >> 6;       // full 64-row super-tiles
    const size_t st0 = (size_t)bid * nst / G1;
    const size_t st1 = ((size_t)bid + 1) * nst / G1;

    if (st0 < st1) {
        stage_super(pred, idx, st0, sbuf[0], ibuf[0], w, lane);

        int cur = 0;
        for (size_t st = st0; st < st1; ++st) {
            if (st + 1 < st1) {
                stage_super(pred, idx, st + 1, sbuf[cur ^ 1], ibuf[cur ^ 1], w, lane);
                asm volatile("s_waitcnt vmcnt(5)" ::: "memory");   // stage(st) landed; st+1 in flight
            } else {
                asm volatile("s_waitcnt vmcnt(0)" ::: "memory");
            }
            __builtin_amdgcn_sched_barrier(0);
            __builtin_amdgcn_s_barrier();        // RAW: every wave's stage(st) chunk landed

            const uint32_t sb32 = (uint32_t)(uintptr_t)&sbuf[cur][0];
            const uint32_t ib32 = (uint32_t)(uintptr_t)&ibuf[cur][0];

            #pragma unroll
            for (int mt = 0; mt < 2; ++mt) {
                #pragma unroll
                for (int kk = 0; kk < 2; ++kk) {
                    const int rowk = mt * 32 + kk * 16 + kg * 8;
                    const uint32_t ia = ib32 + (uint32_t)(rowk * 4);
                    const uint32_t b0 = sb32 + (uint32_t)(rowk * 256) + (uint32_t)col * 4;

                    i32x4 q0, q1;
                    f32x2 p0, p1, p2, p3, p4, p5, p6, p7;
                    asm volatile("ds_read_b128 %0, %1"            : "=v"(q0) : "v"(ia));
                    asm volatile("ds_read_b128 %0, %1 offset:16"  : "=v"(q1) : "v"(ia));
                    // n=0: k pairs (0,1),(2,3) on b0; (4,5),(6,7) on b0+1024
                    asm volatile("ds_read2_b32 %0, %1 offset0:0 offset1:64"     : "=v"(p0) : "v"(b0));
                    asm volatile("ds_read2_b32 %0, %1 offset0:128 offset1:192"  : "=v"(p1) : "v"(b0));
                    asm volatile("ds_read2_b32 %0, %1 offset0:0 offset1:64"     : "=v"(p2) : "v"(b0 + 1024u));
                    asm volatile("ds_read2_b32 %0, %1 offset0:128 offset1:192"  : "=v"(p3) : "v"(b0 + 1024u));
                    // n=1: +128 B
                    asm volatile("ds_read2_b32 %0, %1 offset0:0 offset1:64"     : "=v"(p4) : "v"(b0 + 128u));
                    asm volatile("ds_read2_b32 %0, %1 offset0:128 offset1:192"  : "=v"(p5) : "v"(b0 + 128u));
                    asm volatile("ds_read2_b32 %0, %1 offset0:0 offset1:64"     : "=v"(p6) : "v"(b0 + 1152u));
                    asm volatile("ds_read2_b32 %0, %1 offset0:128 offset1:192"  : "=v"(p7) : "v"(b0 + 1152u));
                    asm volatile("s_waitcnt lgkmcnt(0)" ::: "memory");
                    __builtin_amdgcn_sched_barrier(0);               // rule #18

                    B8 ab;
                    ab.u[0] = cvtpk(q0.x==mycls?1.f:0.f, q0.y==mycls?1.f:0.f);
                    ab.u[1] = cvtpk(q0.z==mycls?1.f:0.f, q0.w==mycls?1.f:0.f);
                    ab.u[2] = cvtpk(q1.x==mycls?1.f:0.f, q1.y==mycls?1.f:0.f);
                    ab.u[3] = cvtpk(q1.z==mycls?1.f:0.f, q1.w==mycls?1.f:0.f);

                    aC = __builtin_amdgcn_mfma_f32_32x32x16_bf16(ab.v, ones, aC, 0, 0, 0);

                    B8 bv, bq;
                    bv.u[0] = cvtpk(p0.x, p0.y);  bq.u[0] = cvtpk(p0.x*p0.x, p0.y*p0.y);
                    bv.u[1] = cvtpk(p1.x, p1.y);  bq.u[1] = cvtpk(p1.x*p1.x, p1.y*p1.y);
                    bv.u[2] = cvtpk(p2.x, p2.y);  bq.u[2] = cvtpk(p2.x*p2.x, p2.y*p2.y);
                    bv.u[3] = cvtpk(p3.x, p3.y);  bq.u[3] = cvtpk(p3.x*p3.x, p3.y*p3.y);
                    aS0 = __builtin_amdgcn_mfma_f32_32x32x16_bf16(ab.v, bv.v, aS0, 0, 0, 0);
                    aQ0 = __builtin_amdgcn_mfma_f32_32x32x16_bf16(ab.v, bq.v, aQ0, 0, 0, 0);

                    bv.u[0] = cvtpk(p4.x, p4.y);  bq.u[0] = cvtpk(p4.x*p4.x, p4.y*p4.y);
                    bv.u[1] = cvtpk(p5.x, p5.y);  bq.u[1] = cvtpk(p5.x*p5.x, p5.y*p5.y);
                    bv.u[2] = cvtpk(p6.x, p6.y);  bq.u[2] = cvtpk(p6.x*p6.x, p6.y*p6.y);
                    bv.u[3] = cvtpk(p7.x, p7.y);  bq.u[3] = cvtpk(p7.x*p7.x, p7.y*p7.y);
                    aS1 = __builtin_amdgcn_mfma_f32_32x32x16_bf16(ab.v, bv.v, aS1, 0, 0, 0);
                    aQ1 = __builtin_amdgcn_mfma_f32_32x32x16_bf16(ab.v, bq.v, aQ1, 0, 0, 0);
                }
            }
            __builtin_amdgcn_s_barrier();        // WAR: all waves done reading buf[cur]
            cur ^= 1;
        }
    }

    // tail rows (nrows % 64), block 0, masked direct loads
    if (bid == 0 && (nrows & 63)) {
        for (size_t base = nst * 64; base < (size_t)nrows; base += 16) {
            int c[8]; float v0[8], v1[8];
            #pragma unroll
            for (int e = 0; e < 8; ++e) {
                size_t kk = base + (size_t)kg * 8 + e;
                bool ok = kk < (size_t)nrows;
                c[e]  = ok ? idx[kk] : -1;
                v0[e] = ok ? pred[kk * 64 + col] : 0.0f;
                v1[e] = ok ? pred[kk * 64 + 32 + col] : 0.0f;
            }
            B8 ab, b0, q0, b1, q1;
            #pragma unroll
            for (int e = 0; e < 4; ++e) {
                ab.u[e] = cvtpk(c[2*e]==mycls?1.f:0.f, c[2*e+1]==mycls?1.f:0.f);
                b0.u[e] = cvtpk(v0[2*e],          v0[2*e+1]);
                q0.u[e] = cvtpk(v0[2*e]*v0[2*e],  v0[2*e+1]*v0[2*e+1]);
                b1.u[e] = cvtpk(v1[2*e],          v1[2*e+1]);
                q1.u[e] = cvtpk(v1[2*e]*v1[2*e],  v1[2*e+1]*v1[2*e+1]);
            }
            aC  = __builtin_amdgcn_mfma_f32_32x32x16_bf16(ab.v, ones, aC,  0, 0, 0);
            aS0 = __builtin_amdgcn_mfma_f32_32x32x16_bf16(ab.v, b0.v, aS0, 0, 0, 0);
            aQ0 = __builtin_amdgcn_mfma_f32_32x32x16_bf16(ab.v, q0.v, aQ0, 0, 0, 0);
            aS1 = __builtin_amdgcn_mfma_f32_32x32x16_bf16(ab.v, b1.v, aS1, 0, 0, 0);
            aQ1 = __builtin_amdgcn_mfma_f32_32x32x16_bf16(ab.v, q1.v, aQ1, 0, 0, 0);
        }
    }

    // epilogue: coalesced per-block partials (or atomic fallback)
    if (!atomicPath) {
        float* pp = part + (size_t)bid * PBLK;
        #pragma unroll
        for (int reg = 0; reg < 16; ++reg) {
            int row = (reg & 3) + 8 * (reg >> 2) + 4 * kg;
            int gm  = w * 32 + row;
            if (gm < NCLS) {
                pp[gm * 64 + col]              = aS0[reg];
                pp[gm * 64 + 32 + col]         = aS1[reg];
                pp[6400 + gm * 64 + col]       = aQ0[reg];
                pp[6400 + gm * 64 + 32 + col]  = aQ1[reg];
                if (col == 0) pp[12800 + gm]   = aC[reg];   // counts (exact ints)
            }
        }
    } else {
        #pragma unroll
        for (int reg = 0; reg < 16; ++reg) {
            int row = (reg & 3) + 8 * (reg >> 2) + 4 * kg;
            int gm  = w * 32 + row;
            if (gm < NCLS) {
                global_fadd(&gacc[gm * 64 + col],             aS0[reg]);
                global_fadd(&gacc[gm * 64 + 32 + col],        aS1[reg]);
                global_fadd(&gacc[6400 + gm * 64 + col],      aQ0[reg]);
                global_fadd(&gacc[6400 + gm * 64 + 32 + col], aQ1[reg]);
                if (col == 0) global_fadd(&gacc[12800 + gm],  aC[reg]);
            }
        }
    }
}

// -------- Kernel 1c: reduce partials, 8-way parallel over blocks ----------
// part layout [G1][PBLK], identity with gacc: gacc[pos] += sum_b part[b][pos]
__global__ __launch_bounds__(256) void reduce_kernel(
    const float* __restrict__ part, float* __restrict__ gacc)
{
    int pos = blockIdx.x * 256 + threadIdx.x;    // 0..12899
    if (pos >= PBLK) return;
    const int bq = G1 / 8;                       // 128
    int b0 = blockIdx.y * bq;

    const float* p = part + (size_t)b0 * PBLK + pos;
    float s0 = 0.f, s1 = 0.f, s2 = 0.f, s3 = 0.f;
    #pragma unroll 1
    for (int b = 0; b + 4 <= bq; b += 4) {
        s0 += p[(size_t)(b + 0) * PBLK];
        s1 += p[(size_t)(b + 1) * PBLK];
        s2 += p[(size_t)(b + 2) * PBLK];
        s3 += p[(size_t)(b + 3) * PBLK];
    }
    global_fadd(&gacc[pos], (s0 + s1) + (s2 + s3));
}

// ---------------- Kernel 2: finalize (unchanged, verified) ----------------
#define MSTR 68

__global__ __launch_bounds__(1024) void finalize_kernel(
    const float* __restrict__ gacc, float* __restrict__ out)
{
    __shared__ float mean_s[NCLS * MSTR];
    __shared__ float colstd[D];
    __shared__ float norms[NCLS];
    __shared__ float redSum[16], redMin[16];
    __shared__ float s_cov;

    const float* gSum = gacc;
    const float* gSq  = gacc + NCLS * D;
    const float* gCnt = gacc + 2 * NCLS * D;

    for (int d = threadIdx.x; d < D; d += 1024) colstd[d] = 0.0f;
    __syncthreads();

    for (int i = threadIdx.x; i < NCLS * D; i += 1024) {
        int c = i >> 6, d = i & 63;
        float cnt = gCnt[c];
        float m   = gSum[i] / cnt;
        float var = (gSq[i] - cnt * m * m) / (cnt - 1.0f);
        float sd  = sqrtf(fmaxf(var, 0.0f));
        mean_s[c * MSTR + d] = m;
        lds_fadd((uint32_t)(uintptr_t)(&colstd[d]), sd);
    }
    asm volatile("s_waitcnt lgkmcnt(0)" ::: "memory");
    __syncthreads();

    if (threadIdx.x < 64) {
        float v = colstd[threadIdx.x];
        v = v * v;
        for (int o = 32; o; o >>= 1) v += __shfl_down(v, o);
        if (threadIdx.x == 0) s_cov = v / (float)NCLS;
    }

    for (int c = threadIdx.x; c < NCLS; c += 1024) {
        const float4* mp = (const float4*)&mean_s[c * MSTR];
        float n = 0.0f;
        #pragma unroll
        for (int d4 = 0; d4 < D / 4; ++d4) {
            float4 a = mp[d4];
            n += a.x * a.x + a.y * a.y + a.z * a.z + a.w * a.w;
        }
        norms[c] = n;
    }
    __syncthreads();

    const int n_pairs = NCLS * (NCLS - 1) / 2;
    float lsum = 0.0f, lmin = INFINITY;
    for (int p = threadIdx.x; p < n_pairs; p += 1024) {
        int i = (int)((1.0f + sqrtf(1.0f + 8.0f * (float)p)) * 0.5f);
        while (i * (i - 1) / 2 > p) --i;
        while ((i + 1) * i / 2 <= p) ++i;
        int j = p - i * (i - 1) / 2;

        const float4* mi = (const float4*)&mean_s[i * MSTR];
        const float4* mj = (const float4*)&mean_s[j * MSTR];
        float dot = 0.0f;
        #pragma unroll
        for (int d4 = 0; d4 < D / 4; ++d4) {
            float4 a = mi[d4], b = mj[d4];
            dot += a.x * b.x + a.y * b.y + a.z * b.z + a.w * b.w;
        }
        float dist = norms[i] + norms[j] - 2.0f * dot;
        lsum += dist;
        lmin = fminf(lmin, dist);
    }

    for (int o = 32; o; o >>= 1) {
        lsum += __shfl_down(lsum, o);
        lmin = fminf(lmin, __shfl_down(lmin, o));
    }
    int ww = threadIdx.x >> 6;
    if ((threadIdx.x & 63) == 0) { redSum[ww] = lsum; redMin[ww] = lmin; }
    __syncthreads();

    if (threadIdx.x == 0) {
        float S = 0.0f, M = INFINITY;
        for (int k = 0; k < 16; ++k) { S += redSum[k]; M = fminf(M, redMin[k]); }
        float md  = S / (float)n_pairs;
        float cov = s_cov;
        float e   = 8.0f - md;
        float loss = 1.0f * cov + 0.1f * e * e;   // C_COEF = 0
        out[0] = loss;
        out[1] = md;
        out[2] = M;
        out[3] = cov;
    }
}

extern "C" void kernel_launch(void* const* d_in, const int* in_sizes, int n_in,
                              void* d_out, int out_size, void* d_ws, size_t ws_size,
                              hipStream_t stream) {
    const float* pred = (const float*)d_in[0];
    const int*   gidx = (const int*)d_in[1];
    float* out = (float*)d_out;
    int nrows = in_sizes[1];   // 2,000,000 rows

    const size_t partFloats = (size_t)G1 * PBLK;   // 13.2M floats = 52.8 MB

    if (ws_size >= (partFloats + GACC_FLOATS) * sizeof(float)) {
        float* part = (float*)d_ws;
        float* gacc = part + partFloats;
        hipMemsetAsync(gacc, 0, GACC_FLOATS * sizeof(float), stream);
        seg_mfma_kernel<<<G1, BLK, 0, stream>>>(pred, gidx, part, gacc, nrows, 0);
        dim3 gridR((PBLK + 255) / 256, 8);
        reduce_kernel<<<gridR, 256, 0, stream>>>(part, gacc);
        finalize_kernel<<<1, 1024, 0, stream>>>(gacc, out);
    } else {
        float* gacc = (float*)d_ws;
        hipMemsetAsync(gacc, 0, GACC_FLOATS * sizeof(float), stream);
        seg_mfma_kernel<<<G1, BLK, 0, stream>>>(pred, gidx, nullptr, gacc, nrows, 1);
        finalize_kernel<<<1, 1024, 0, stream>>>(gacc, out);
    }
}

// Round 10
// 154.978 us; speedup vs baseline: 2.0009x; 1.0479x over previous
//
#include <hip/hip_runtime.h>
#include <math.h>

#define NCLS 100
#define D 64
#define GACC_FLOATS (NCLS * D * 2 + NCLS)   // 12900: sums[6400] sq[6400] cnt[100]
#define G1 768         // seg blocks (3 per CU)
#define BLK 256
#define PBLK 12800     // per-block partial floats: sums[6400] sq[6400]
#define SUPF 4096      // super-tile floats: 64 rows x 64 cols (16 KB)

typedef __attribute__((ext_vector_type(8)))  short bf16x8;
typedef __attribute__((ext_vector_type(16))) float f32x16;
typedef __attribute__((ext_vector_type(2)))  float f32x2;
typedef __attribute__((ext_vector_type(4)))  int   i32x4;

#define ZV16 {0.f,0.f,0.f,0.f,0.f,0.f,0.f,0.f,0.f,0.f,0.f,0.f,0.f,0.f,0.f,0.f}

union B8 { uint32_t u[4]; bf16x8 v; };

// packed f32->bf16 RNE; used for BOTH A and B so pair-order convention cancels
__device__ __forceinline__ uint32_t cvtpk(float lo, float hi) {
    uint32_t r;
    asm("v_cvt_pk_bf16_f32 %0, %1, %2" : "=v"(r) : "v"(lo), "v"(hi));
    return r;
}

__device__ __forceinline__ void global_fadd(float* p, float v) {
    asm volatile("global_atomic_add_f32 %0, %1, off"
                 :: "v"((uint64_t)(uintptr_t)p), "v"(v));
}

__device__ __forceinline__ void lds_fadd(uint32_t byteoff, float v) {
    asm volatile("ds_add_f32 %0, %1" :: "v"(byteoff), "v"(v));
}

// stage one 64x64 f32 super-tile (16 KB) + its 64 idx ints into LDS.
// 5 gll per wave (idx gll redundant across the 4 waves - same data, benign).
__device__ __forceinline__ void stage_super(const float* __restrict__ pred,
                                            const int* __restrict__ idx, size_t st,
                                            float* sb, int* ib, int w, int lane) {
    const float* src = pred + st * SUPF;
    #pragma unroll
    for (int r = 0; r < 4; ++r) {
        int c = r * 4 + w;                       // 16 chunks of 256 floats
        const float* gs = src + (size_t)c * 256 + (size_t)lane * 4;
        float* ls = sb + c * 256;
        __builtin_amdgcn_global_load_lds(
            (const __attribute__((address_space(1))) uint32_t*)gs,
            (__attribute__((address_space(3))) uint32_t*)ls, 16, 0, 0);
    }
    const int* gi = idx + st * 64 + lane;
    __builtin_amdgcn_global_load_lds(
        (const __attribute__((address_space(1))) uint32_t*)gi,
        (__attribute__((address_space(3))) uint32_t*)ib, 4, 0, 0);
}

// ---------------- Kernel 1: segmented sum/sumsq via one-hot MFMA ----------
// Wave w: classes [32w,32w+32). A: row=lane&31(class), k=(lane>>5)*8+e.
// B: col=lane&31, same k. C/D: col=lane&31, row=(reg&3)+8*(reg>>2)+4*(lane>>5).
// [fragment conventions validated R3-R9, absmax ~2e-4]
// Counted-vmcnt pipeline (T3/T4): raw s_barrier, vmcnt(5) NOT 0 in main loop.
// Register diet: 4 accs = 64 AGPR; (256,3) bound -> cap 170 regs, 3 waves/SIMD
// (R8's (256,4)=128-cap spilled; R9's unbounded ~180 regs = 2 waves/SIMD).
__global__ __launch_bounds__(BLK, 3) void seg_mfma_kernel(
    const float* __restrict__ pred, const int* __restrict__ idx,
    float* __restrict__ part, float* __restrict__ gacc,
    int nrows, int atomicPath)
{
    __shared__ float sbuf[2][SUPF];              // 2 x 16 KB
    __shared__ int   ibuf[2][64];                // 2 x 256 B

    const int bid   = blockIdx.x;
    const int tid   = threadIdx.x;
    const int lane  = tid & 63;
    const int w     = tid >> 6;
    const int col   = lane & 31;
    const int kg    = lane >> 5;
    const int mycls = w * 32 + col;

    f32x16 aS0 = ZV16, aS1 = ZV16, aQ0 = ZV16, aQ1 = ZV16;

    const size_t nst = (size_t)nrows >> 6;       // full 64-row super-tiles
    const size_t st0 = (size_t)bid * nst / G1;
    const size_t st1 = ((size_t)bid + 1) * nst / G1;

    if (st0 < st1) {
        stage_super(pred, idx, st0, sbuf[0], ibuf[0], w, lane);

        int cur = 0;
        for (size_t st = st0; st < st1; ++st) {
            if (st + 1 < st1) {
                stage_super(pred, idx, st + 1, sbuf[cur ^ 1], ibuf[cur ^ 1], w, lane);
                asm volatile("s_waitcnt vmcnt(5)" ::: "memory");   // stage(st) landed; st+1 in flight
            } else {
                asm volatile("s_waitcnt vmcnt(0)" ::: "memory");
            }
            __builtin_amdgcn_sched_barrier(0);
            __builtin_amdgcn_s_barrier();        // RAW: every wave's stage(st) chunk landed

            const uint32_t sb32 = (uint32_t)(uintptr_t)&sbuf[cur][0];
            const uint32_t ib32 = (uint32_t)(uintptr_t)&ibuf[cur][0];

            #pragma unroll
            for (int mt = 0; mt < 2; ++mt) {
                #pragma unroll
                for (int kk = 0; kk < 2; ++kk) {
                    const int rowk = mt * 32 + kk * 16 + kg * 8;
                    const uint32_t ia = ib32 + (uint32_t)(rowk * 4);
                    const uint32_t b0 = sb32 + (uint32_t)(rowk * 256) + (uint32_t)col * 4;

                    i32x4 q0, q1;
                    f32x2 p0, p1, p2, p3, p4, p5, p6, p7;
                    asm volatile("ds_read_b128 %0, %1"            : "=v"(q0) : "v"(ia));
                    asm volatile("ds_read_b128 %0, %1 offset:16"  : "=v"(q1) : "v"(ia));
                    // n=0: k pairs (0,1),(2,3) on b0; (4,5),(6,7) on b0+1024
                    asm volatile("ds_read2_b32 %0, %1 offset0:0 offset1:64"     : "=v"(p0) : "v"(b0));
                    asm volatile("ds_read2_b32 %0, %1 offset0:128 offset1:192"  : "=v"(p1) : "v"(b0));
                    asm volatile("ds_read2_b32 %0, %1 offset0:0 offset1:64"     : "=v"(p2) : "v"(b0 + 1024u));
                    asm volatile("ds_read2_b32 %0, %1 offset0:128 offset1:192"  : "=v"(p3) : "v"(b0 + 1024u));
                    // n=1: +128 B
                    asm volatile("ds_read2_b32 %0, %1 offset0:0 offset1:64"     : "=v"(p4) : "v"(b0 + 128u));
                    asm volatile("ds_read2_b32 %0, %1 offset0:128 offset1:192"  : "=v"(p5) : "v"(b0 + 128u));
                    asm volatile("ds_read2_b32 %0, %1 offset0:0 offset1:64"     : "=v"(p6) : "v"(b0 + 1152u));
                    asm volatile("ds_read2_b32 %0, %1 offset0:128 offset1:192"  : "=v"(p7) : "v"(b0 + 1152u));
                    asm volatile("s_waitcnt lgkmcnt(0)" ::: "memory");
                    __builtin_amdgcn_sched_barrier(0);               // rule #18

                    B8 ab;
                    ab.u[0] = cvtpk(q0.x==mycls?1.f:0.f, q0.y==mycls?1.f:0.f);
                    ab.u[1] = cvtpk(q0.z==mycls?1.f:0.f, q0.w==mycls?1.f:0.f);
                    ab.u[2] = cvtpk(q1.x==mycls?1.f:0.f, q1.y==mycls?1.f:0.f);
                    ab.u[3] = cvtpk(q1.z==mycls?1.f:0.f, q1.w==mycls?1.f:0.f);

                    B8 bv, bq;
                    bv.u[0] = cvtpk(p0.x, p0.y);  bq.u[0] = cvtpk(p0.x*p0.x, p0.y*p0.y);
                    bv.u[1] = cvtpk(p1.x, p1.y);  bq.u[1] = cvtpk(p1.x*p1.x, p1.y*p1.y);
                    bv.u[2] = cvtpk(p2.x, p2.y);  bq.u[2] = cvtpk(p2.x*p2.x, p2.y*p2.y);
                    bv.u[3] = cvtpk(p3.x, p3.y);  bq.u[3] = cvtpk(p3.x*p3.x, p3.y*p3.y);
                    aS0 = __builtin_amdgcn_mfma_f32_32x32x16_bf16(ab.v, bv.v, aS0, 0, 0, 0);
                    aQ0 = __builtin_amdgcn_mfma_f32_32x32x16_bf16(ab.v, bq.v, aQ0, 0, 0, 0);

                    bv.u[0] = cvtpk(p4.x, p4.y);  bq.u[0] = cvtpk(p4.x*p4.x, p4.y*p4.y);
                    bv.u[1] = cvtpk(p5.x, p5.y);  bq.u[1] = cvtpk(p5.x*p5.x, p5.y*p5.y);
                    bv.u[2] = cvtpk(p6.x, p6.y);  bq.u[2] = cvtpk(p6.x*p6.x, p6.y*p6.y);
                    bv.u[3] = cvtpk(p7.x, p7.y);  bq.u[3] = cvtpk(p7.x*p7.x, p7.y*p7.y);
                    aS1 = __builtin_amdgcn_mfma_f32_32x32x16_bf16(ab.v, bv.v, aS1, 0, 0, 0);
                    aQ1 = __builtin_amdgcn_mfma_f32_32x32x16_bf16(ab.v, bq.v, aQ1, 0, 0, 0);
                }
            }
            __builtin_amdgcn_s_barrier();        // WAR: all waves done reading buf[cur]
            cur ^= 1;
        }
    }

    // tail rows (nrows % 64), block 0, masked direct loads
    if (bid == 0 && (nrows & 63)) {
        for (size_t base = nst * 64; base < (size_t)nrows; base += 16) {
            int c[8]; float v0[8], v1[8];
            #pragma unroll
            for (int e = 0; e < 8; ++e) {
                size_t kk = base + (size_t)kg * 8 + e;
                bool ok = kk < (size_t)nrows;
                c[e]  = ok ? idx[kk] : -1;
                v0[e] = ok ? pred[kk * 64 + col] : 0.0f;
                v1[e] = ok ? pred[kk * 64 + 32 + col] : 0.0f;
            }
            B8 ab, b0, q0, b1, q1;
            #pragma unroll
            for (int e = 0; e < 4; ++e) {
                ab.u[e] = cvtpk(c[2*e]==mycls?1.f:0.f, c[2*e+1]==mycls?1.f:0.f);
                b0.u[e] = cvtpk(v0[2*e],          v0[2*e+1]);
                q0.u[e] = cvtpk(v0[2*e]*v0[2*e],  v0[2*e+1]*v0[2*e+1]);
                b1.u[e] = cvtpk(v1[2*e],          v1[2*e+1]);
                q1.u[e] = cvtpk(v1[2*e]*v1[2*e],  v1[2*e+1]*v1[2*e+1]);
            }
            aS0 = __builtin_amdgcn_mfma_f32_32x32x16_bf16(ab.v, b0.v, aS0, 0, 0, 0);
            aQ0 = __builtin_amdgcn_mfma_f32_32x32x16_bf16(ab.v, q0.v, aQ0, 0, 0, 0);
            aS1 = __builtin_amdgcn_mfma_f32_32x32x16_bf16(ab.v, b1.v, aS1, 0, 0, 0);
            aQ1 = __builtin_amdgcn_mfma_f32_32x32x16_bf16(ab.v, q1.v, aQ1, 0, 0, 0);
        }
    }

    // epilogue: coalesced per-block partials (or atomic fallback)
    if (!atomicPath) {
        float* pp = part + (size_t)bid * PBLK;
        #pragma unroll
        for (int reg = 0; reg < 16; ++reg) {
            int row = (reg & 3) + 8 * (reg >> 2) + 4 * kg;
            int gm  = w * 32 + row;
            if (gm < NCLS) {
                pp[gm * 64 + col]              = aS0[reg];
                pp[gm * 64 + 32 + col]         = aS1[reg];
                pp[6400 + gm * 64 + col]       = aQ0[reg];
                pp[6400 + gm * 64 + 32 + col]  = aQ1[reg];
            }
        }
    } else {
        #pragma unroll
        for (int reg = 0; reg < 16; ++reg) {
            int row = (reg & 3) + 8 * (reg >> 2) + 4 * kg;
            int gm  = w * 32 + row;
            if (gm < NCLS) {
                global_fadd(&gacc[gm * 64 + col],             aS0[reg]);
                global_fadd(&gacc[gm * 64 + 32 + col],        aS1[reg]);
                global_fadd(&gacc[6400 + gm * 64 + col],      aQ0[reg]);
                global_fadd(&gacc[6400 + gm * 64 + 32 + col], aQ1[reg]);
            }
        }
    }
}

// ---------------- Kernel 1b: standalone hist (atomic-fallback path only) --
__global__ __launch_bounds__(256) void hist_kernel(
    const int* __restrict__ idx, float* __restrict__ gcnt, int nrows)
{
    __shared__ uint32_t hh[NCLS];
    for (int i = threadIdx.x; i < NCLS; i += 256) hh[i] = 0u;
    __syncthreads();
    const int tid = blockIdx.x * 256 + threadIdx.x;
    const int stride = gridDim.x * 256;
    const int n4 = nrows >> 2;
    for (int i = tid; i < n4; i += stride) {
        int4 c = ((const int4*)idx)[i];
        atomicAdd(&hh[c.x], 1u); atomicAdd(&hh[c.y], 1u);
        atomicAdd(&hh[c.z], 1u); atomicAdd(&hh[c.w], 1u);
    }
    for (int i = (n4 << 2) + tid; i < nrows; i += stride)
        atomicAdd(&hh[idx[i]], 1u);
    __syncthreads();
    for (int i = threadIdx.x; i < NCLS; i += 256)
        if (hh[i]) global_fadd(&gcnt[i], (float)hh[i]);
}

// -------- Kernel 1c: reduce partials + counts hist, fused -----------------
// grid (50, 9): y<8 -> partial-sum slice over 96 blocks; y==8 -> idx hist
// (8 MB read overlapped with the 39 MB partial read; near-free).
__global__ __launch_bounds__(256) void reduce_kernel(
    const float* __restrict__ part, const int* __restrict__ idx,
    float* __restrict__ gacc, int nrows)
{
    if (blockIdx.y == 8) {
        __shared__ uint32_t hh[NCLS];
        for (int i = threadIdx.x; i < NCLS; i += 256) hh[i] = 0u;
        __syncthreads();
        const int tid = blockIdx.x * 256 + threadIdx.x;
        const int stride = gridDim.x * 256;
        const int n4 = nrows >> 2;
        for (int i = tid; i < n4; i += stride) {
            int4 c = ((const int4*)idx)[i];
            atomicAdd(&hh[c.x], 1u); atomicAdd(&hh[c.y], 1u);
            atomicAdd(&hh[c.z], 1u); atomicAdd(&hh[c.w], 1u);
        }
        for (int i = (n4 << 2) + tid; i < nrows; i += stride)
            atomicAdd(&hh[idx[i]], 1u);
        __syncthreads();
        for (int i = threadIdx.x; i < NCLS; i += 256)
            if (hh[i]) global_fadd(&gacc[12800 + i], (float)hh[i]);
        return;
    }

    int pos = blockIdx.x * 256 + threadIdx.x;    // 0..12799
    if (pos >= PBLK) return;
    const int bq = G1 / 8;                       // 96
    int b0 = blockIdx.y * bq;

    const float* p = part + (size_t)b0 * PBLK + pos;
    float s0 = 0.f, s1 = 0.f, s2 = 0.f, s3 = 0.f;
    #pragma unroll 1
    for (int b = 0; b + 4 <= bq; b += 4) {
        s0 += p[(size_t)(b + 0) * PBLK];
        s1 += p[(size_t)(b + 1) * PBLK];
        s2 += p[(size_t)(b + 2) * PBLK];
        s3 += p[(size_t)(b + 3) * PBLK];
    }
    global_fadd(&gacc[pos], (s0 + s1) + (s2 + s3));
}

// ---------------- Kernel 2: finalize (unchanged, verified) ----------------
#define MSTR 68

__global__ __launch_bounds__(1024) void finalize_kernel(
    const float* __restrict__ gacc, float* __restrict__ out)
{
    __shared__ float mean_s[NCLS * MSTR];
    __shared__ float colstd[D];
    __shared__ float norms[NCLS];
    __shared__ float redSum[16], redMin[16];
    __shared__ float s_cov;

    const float* gSum = gacc;
    const float* gSq  = gacc + NCLS * D;
    const float* gCnt = gacc + 2 * NCLS * D;

    for (int d = threadIdx.x; d < D; d += 1024) colstd[d] = 0.0f;
    __syncthreads();

    for (int i = threadIdx.x; i < NCLS * D; i += 1024) {
        int c = i >> 6, d = i & 63;
        float cnt = gCnt[c];
        float m   = gSum[i] / cnt;
        float var = (gSq[i] - cnt * m * m) / (cnt - 1.0f);
        float sd  = sqrtf(fmaxf(var, 0.0f));
        mean_s[c * MSTR + d] = m;
        lds_fadd((uint32_t)(uintptr_t)(&colstd[d]), sd);
    }
    asm volatile("s_waitcnt lgkmcnt(0)" ::: "memory");
    __syncthreads();

    if (threadIdx.x < 64) {
        float v = colstd[threadIdx.x];
        v = v * v;
        for (int o = 32; o; o >>= 1) v += __shfl_down(v, o);
        if (threadIdx.x == 0) s_cov = v / (float)NCLS;
    }

    for (int c = threadIdx.x; c < NCLS; c += 1024) {
        const float4* mp = (const float4*)&mean_s[c * MSTR];
        float n = 0.0f;
        #pragma unroll
        for (int d4 = 0; d4 < D / 4; ++d4) {
            float4 a = mp[d4];
            n += a.x * a.x + a.y * a.y + a.z * a.z + a.w * a.w;
        }
        norms[c] = n;
    }
    __syncthreads();

    const int n_pairs = NCLS * (NCLS - 1) / 2;
    float lsum = 0.0f, lmin = INFINITY;
    for (int p = threadIdx.x; p < n_pairs; p += 1024) {
        int i = (int)((1.0f + sqrtf(1.0f + 8.0f * (float)p)) * 0.5f);
        while (i * (i - 1) / 2 > p) --i;
        while ((i + 1) * i / 2 <= p) ++i;
        int j = p - i * (i - 1) / 2;

        const float4* mi = (const float4*)&mean_s[i * MSTR];
        const float4* mj = (const float4*)&mean_s[j * MSTR];
        float dot = 0.0f;
        #pragma unroll
        for (int d4 = 0; d4 < D / 4; ++d4) {
            float4 a = mi[d4], b = mj[d4];
            dot += a.x * b.x + a.y * b.y + a.z * b.z + a.w * b.w;
        }
        float dist = norms[i] + norms[j] - 2.0f * dot;
        lsum += dist;
        lmin = fminf(lmin, dist);
    }

    for (int o = 32; o; o >>= 1) {
        lsum += __shfl_down(lsum, o);
        lmin = fminf(lmin, __shfl_down(lmin, o));
    }
    int ww = threadIdx.x >> 6;
    if ((threadIdx.x & 63) == 0) { redSum[ww] = lsum; redMin[ww] = lmin; }
    __syncthreads();

    if (threadIdx.x == 0) {
        float S = 0.0f, M = INFINITY;
        for (int k = 0; k < 16; ++k) { S += redSum[k]; M = fminf(M, redMin[k]); }
        float md  = S / (float)n_pairs;
        float cov = s_cov;
        float e   = 8.0f - md;
        float loss = 1.0f * cov + 0.1f * e * e;   // C_COEF = 0
        out[0] = loss;
        out[1] = md;
        out[2] = M;
        out[3] = cov;
    }
}

extern "C" void kernel_launch(void* const* d_in, const int* in_sizes, int n_in,
                              void* d_out, int out_size, void* d_ws, size_t ws_size,
                              hipStream_t stream) {
    const float* pred = (const float*)d_in[0];
    const int*   gidx = (const int*)d_in[1];
    float* out = (float*)d_out;
    int nrows = in_sizes[1];   // 2,000,000 rows

    const size_t partFloats = (size_t)G1 * PBLK;   // 9.83M floats = 39.3 MB

    if (ws_size >= (partFloats + GACC_FLOATS) * sizeof(float)) {
        float* part = (float*)d_ws;
        float* gacc = part + partFloats;
        hipMemsetAsync(gacc, 0, GACC_FLOATS * sizeof(float), stream);
        seg_mfma_kernel<<<G1, BLK, 0, stream>>>(pred, gidx, part, gacc, nrows, 0);
        dim3 gridR(PBLK / 256, 9);
        reduce_kernel<<<gridR, 256, 0, stream>>>(part, gidx, gacc, nrows);
        finalize_kernel<<<1, 1024, 0, stream>>>(gacc, out);
    } else {
        float* gacc = (float*)d_ws;
        hipMemsetAsync(gacc, 0, GACC_FLOATS * sizeof(float), stream);
        seg_mfma_kernel<<<G1, BLK, 0, stream>>>(pred, gidx, nullptr, gacc, nrows, 1);
        hist_kernel<<<1024, 256, 0, stream>>>(gidx, gacc + 12800, nrows);
        finalize_kernel<<<1, 1024, 0, stream>>>(gacc, out);
    }
}